// Round 12
// baseline (1426.275 us; speedup 1.0000x reference)
//
#include <hip/hip_runtime.h>

#define BB 4
#define LL 512
#define DD 768
#define NLAYER 12
#define DI 1536
#define NS 16
#define KC 4
#define RR 48
#define MROWS (BB*LL)   // 2048
#define E2 (2*DI)       // 3072
#define EPSV 1e-5f
#define LOG2E 1.4426950408889634f
#define XPZ 12          // xp split-K factor (2 K-steps each)
#define OZ 2            // out-proj split-K factor
// scan geometry: 32 chunks x 8 d-lanes per block
#define SCH 32
#define SLC (LL/SCH)    // 16
#define SDL 8
#define SSTR (SCH*16 + 5)  // 517: LDS row stride per d-lane

typedef __attribute__((ext_vector_type(8))) short bf16x8;
typedef __attribute__((ext_vector_type(4))) float f32x4;

#define GLL16(g, l) __builtin_amdgcn_global_load_lds( \
    (const __attribute__((address_space(1))) void*)(g), \
    (__attribute__((address_space(3))) void*)(l), 16, 0, 0)

__device__ inline float hw_exp2(float x) { return __builtin_amdgcn_exp2f(x); }

__device__ inline ushort f2bf(float f) {
  union { float f; unsigned u; } v; v.f = f;
  unsigned u = v.u;
  unsigned r = (u + 0x7fffu + ((u >> 16) & 1u)) >> 16;
  return (ushort)r;
}
__device__ inline float bf2f(ushort u) {
  union { unsigned u; float f; } v; v.u = ((unsigned)u) << 16; return v.f;
}

__device__ inline float block_sum(float v, volatile float* red) {
  #pragma unroll
  for (int o = 32; o > 0; o >>= 1) v += __shfl_down(v, o);
  if ((threadIdx.x & 63) == 0) red[threadIdx.x >> 6] = v;
  __syncthreads();
  float t = red[0] + red[1] + red[2] + red[3];
  __syncthreads();
  return t;
}

// ---------------- cvtA: in_W + out_W f32->bf16 ----------------
__global__ __launch_bounds__(256) void k_cvtA(const float* __restrict__ inW,
    const float* __restrict__ outW, ushort* __restrict__ wIn,
    ushort* __restrict__ wOut) {
  int i = blockIdx.x * 256 + threadIdx.x;
  const int nIn = NLAYER * E2 * DD / 4;
  const int nOut = NLAYER * DD * DI / 4;
  if (i < nIn) {
    float4 v = ((const float4*)inW)[i];
    ushort4 o = { f2bf(v.x), f2bf(v.y), f2bf(v.z), f2bf(v.w) };
    ((ushort4*)wIn)[i] = o;
  } else if (i < nIn + nOut) {
    int j = i - nIn;
    float4 v = ((const float4*)outW)[j];
    ushort4 o = { f2bf(v.x), f2bf(v.y), f2bf(v.z), f2bf(v.w) };
    ((ushort4*)wOut)[j] = o;
  }
}

// ---------------- cvtB: xp_W bf16; dt_W bf16 64-pad; conv_W transpose ----------------
__global__ __launch_bounds__(256) void k_cvtB(const float* __restrict__ xpW,
    const float* __restrict__ dtW, const float* __restrict__ convW,
    ushort* __restrict__ wXp, ushort* __restrict__ wDt, float* __restrict__ convWt) {
  int i = blockIdx.x * 256 + threadIdx.x;
  const int n0 = NLAYER * 80 * DI / 4;
  const int n1 = NLAYER * DI * 64;
  const int n2 = NLAYER * DI * 4;
  if (i < n0) {
    float4 v = ((const float4*)xpW)[i];
    ushort4 o = { f2bf(v.x), f2bf(v.y), f2bf(v.z), f2bf(v.w) };
    ((ushort4*)wXp)[i] = o;
  } else if (i < n0 + n1) {
    int j = i - n0;
    int r = j >> 6, c = j & 63;
    wDt[j] = (c < RR) ? f2bf(dtW[(size_t)r * RR + c]) : (ushort)0;
  } else if (i < n0 + n1 + n2) {
    int j = i - n0 - n1;
    int l = j / (DI * 4);
    int rem = j - l * (DI * 4);
    int d = rem >> 2, k = rem & 3;
    convWt[(size_t)l * 4 * DI + k * DI + d] = convW[(size_t)l * DI * 4 + d * 4 + k];
  }
}

// ---------------- embedding: resid = wte[ids] + wpe ----------------
__global__ __launch_bounds__(256) void k_embed(const int* __restrict__ ids,
    const float* __restrict__ wte, const float* __restrict__ wpe,
    float* __restrict__ resid) {
  const int nd4 = DD / 4;
  int i = blockIdx.x * 256 + threadIdx.x;
  if (i >= MROWS * nd4) return;
  int m = i / nd4, d4 = i - m * nd4;
  int l = m & (LL - 1);
  int tok = ids[m];
  float4 a = ((const float4*)wte)[(size_t)tok * nd4 + d4];
  float4 b = ((const float4*)wpe)[(size_t)l * nd4 + d4];
  float4 o; o.x = a.x + b.x; o.y = a.y + b.y; o.z = a.z + b.z; o.w = a.w + b.w;
  ((float4*)resid)[i] = o;
}

// ---------------- fused residual add (OZ partials) + layernorm -> bf16 ----------------
__global__ __launch_bounds__(256) void k_ln(const float* __restrict__ hidP,
    float* __restrict__ resid, const float* __restrict__ g, const float* __restrict__ b,
    ushort* __restrict__ hbf, int addHidden) {
  __shared__ float red[4];
  int m = blockIdx.x, t = threadIdx.x;
  size_t base = (size_t)m * DD;
  float x0 = resid[base + t], x1 = resid[base + t + 256], x2 = resid[base + t + 512];
  if (addHidden) {
    #pragma unroll
    for (int z = 0; z < OZ; ++z) {
      size_t bz = (size_t)z * MROWS * DD + base;
      x0 += hidP[bz + t]; x1 += hidP[bz + t + 256]; x2 += hidP[bz + t + 512];
    }
    resid[base + t] = x0; resid[base + t + 256] = x1; resid[base + t + 512] = x2;
  }
  float S  = block_sum(x0 + x1 + x2, red);
  float S2 = block_sum(x0*x0 + x1*x1 + x2*x2, red);
  float mu = S * (1.f / DD);
  float var = S2 * (1.f / DD) - mu * mu;
  float rs = rsqrtf(var + EPSV);
  hbf[base + t]       = f2bf((x0 - mu) * rs * g[t]       + b[t]);
  hbf[base + t + 256] = f2bf((x1 - mu) * rs * g[t + 256] + b[t + 256]);
  hbf[base + t + 512] = f2bf((x2 - mu) * rs * g[t + 512] + b[t + 512]);
}

// ---------------- 64xNT (MxN) MFMA GEMM, BK=64, NT, bf16 in ----------------
// OM=0: f32 partials (z-offset). OM=1: bf16. OM=2: f32 softplus(acc + dtb[col]).
template<int OM, int NT>
__global__ __launch_bounds__(256) void k_gemm64(const ushort* __restrict__ A,
    const ushort* __restrict__ Bw, void* __restrict__ Cv, const float* __restrict__ dtb,
    int N, int K, int kSteps) {
  constexpr int NR = NT / 32;       // acc columns (4 for NT=128, 2 for NT=64)
  __shared__ ushort lA[64 * 64];
  __shared__ ushort lB[NT * 64];
  int tid = threadIdx.x;
  int wid = tid >> 6, lane = tid & 63;
  int tm = blockIdx.y * 64, tn = blockIdx.x * NT;
  int kBase = blockIdx.z * kSteps * 64;
  int wr = (wid >> 1) * 32, wc = (wid & 1) * (NT / 2);
  int fr = lane & 15, kg = lane >> 4;
  int sR = lane >> 3;
  int sC = ((lane & 7) ^ sR) * 8;
  f32x4 acc[2][NR];
  #pragma unroll
  for (int mi = 0; mi < 2; ++mi)
    #pragma unroll
    for (int ni = 0; ni < NR; ++ni)
      acc[mi][ni] = {0.f, 0.f, 0.f, 0.f};

  for (int ks = 0; ks < kSteps; ++ks) {
    int k0 = kBase + ks * 64;
    #pragma unroll
    for (int i = 0; i < 2; ++i) {
      int r0 = wid * 16 + i * 8;
      GLL16(A + (size_t)(tm + r0 + sR) * K + k0 + sC, &lA[r0 * 64]);
    }
    #pragma unroll
    for (int i = 0; i < NR; ++i) {
      int r0 = wid * (NT / 4) + i * 8;
      int brow = tn + r0 + sR;
      if (brow > N - 1) brow = N - 1;
      GLL16(Bw + (size_t)brow * K + k0 + sC, &lB[r0 * 64]);
    }
    __syncthreads();
    #pragma unroll
    for (int k2 = 0; k2 < 2; ++k2) {
      bf16x8 af[2], bfr[NR];
      #pragma unroll
      for (int mi = 0; mi < 2; ++mi)
        af[mi] = *(const bf16x8*)&lA[(wr + mi * 16 + fr) * 64 + (((k2 * 4 + kg) ^ (fr & 7)) * 8)];
      #pragma unroll
      for (int ni = 0; ni < NR; ++ni)
        bfr[ni] = *(const bf16x8*)&lB[(wc + ni * 16 + fr) * 64 + (((k2 * 4 + kg) ^ (fr & 7)) * 8)];
      #pragma unroll
      for (int mi = 0; mi < 2; ++mi)
        #pragma unroll
        for (int ni = 0; ni < NR; ++ni)
          acc[mi][ni] = __builtin_amdgcn_mfma_f32_16x16x32_bf16(af[mi], bfr[ni], acc[mi][ni], 0, 0, 0);
    }
    __syncthreads();
  }
  int crow0 = tm + wr + kg * 4;
  int ccol0 = tn + wc + fr;
  if (OM == 0) {
    float* C = (float*)Cv + (size_t)blockIdx.z * ((size_t)gridDim.y * 64) * N;
    #pragma unroll
    for (int mi = 0; mi < 2; ++mi)
      #pragma unroll
      for (int ni = 0; ni < NR; ++ni) {
        int cc = ccol0 + ni * 16;
        if (cc < N) {
          #pragma unroll
          for (int j = 0; j < 4; ++j)
            C[(size_t)(crow0 + mi * 16 + j) * N + cc] = acc[mi][ni][j];
        }
      }
  } else if (OM == 1) {
    ushort* C = (ushort*)Cv;
    #pragma unroll
    for (int mi = 0; mi < 2; ++mi)
      #pragma unroll
      for (int ni = 0; ni < NR; ++ni) {
        int cc = ccol0 + ni * 16;
        if (cc < N) {
          #pragma unroll
          for (int j = 0; j < 4; ++j)
            C[(size_t)(crow0 + mi * 16 + j) * N + cc] = f2bf(acc[mi][ni][j]);
        }
      }
  } else {
    float* C = (float*)Cv;
    #pragma unroll
    for (int mi = 0; mi < 2; ++mi)
      #pragma unroll
      for (int ni = 0; ni < NR; ++ni) {
        int cc = ccol0 + ni * 16;
        if (cc < N) {
          float bv = dtb[cc];
          #pragma unroll
          for (int j = 0; j < 4; ++j) {
            float x = acc[mi][ni][j] + bv;
            float sp = (x > 20.f) ? x : log1pf(__expf(x));
            C[(size_t)(crow0 + mi * 16 + j) * N + cc] = sp;
          }
        }
      }
  }
}

// ---------------- conv-fused xp GEMM (64-row, 2 K-steps/z): conv+silu in A-staging ----------------
// grid (1, MROWS/64, XPZ); z owns 128 channels.
__global__ __launch_bounds__(256) void k_xpconv(const ushort* __restrict__ xz,
    const ushort* __restrict__ wXpL, const float* __restrict__ cwt,
    const float* __restrict__ cbl, ushort* __restrict__ xibf,
    float* __restrict__ xpPart) {
  __shared__ ushort lA[64 * 64];
  __shared__ ushort lB[128 * 64];
  int tid = threadIdx.x;
  int wid = tid >> 6, lane = tid & 63;
  int tm2 = blockIdx.y * 64;
  int kBase = blockIdx.z * 128;
  int wr = (wid >> 1) * 32, wc = (wid & 1) * 64;
  int fr = lane & 15, kg = lane >> 4;
  int sR = lane >> 3, sC = ((lane & 7) ^ sR) * 8;
  f32x4 acc[2][4];
  #pragma unroll
  for (int mi = 0; mi < 2; ++mi)
    #pragma unroll
    for (int ni = 0; ni < 4; ++ni)
      acc[mi][ni] = {0.f, 0.f, 0.f, 0.f};
  for (int ks = 0; ks < 2; ++ks) {
    int k0 = kBase + ks * 64;
    #pragma unroll
    for (int i2 = 0; i2 < 4; ++i2) {
      int r0 = wid * 32 + i2 * 8;
      int brow = r0 + sR;
      if (brow > 79) brow = 79;
      GLL16(wXpL + (size_t)brow * DI + k0 + sC, &lB[r0 * 64]);
    }
    #pragma unroll
    for (int c2 = 0; c2 < 2; ++c2) {
      int chunk = tid + c2 * 256;
      int row = chunk >> 3, cc8 = chunk & 7;
      int m = tm2 + row, l = m & (LL - 1);
      int gc = k0 + cc8 * 8;
      float a8[8];
      {
        float4 a = *(const float4*)&cbl[gc];
        float4 b = *(const float4*)&cbl[gc + 4];
        a8[0] = a.x; a8[1] = a.y; a8[2] = a.z; a8[3] = a.w;
        a8[4] = b.x; a8[5] = b.y; a8[6] = b.z; a8[7] = b.w;
      }
      #pragma unroll
      for (int t = 0; t < 4; ++t) {
        if (l - 3 + t >= 0) {
          float4 a = *(const float4*)&cwt[t * DI + gc];
          float4 b = *(const float4*)&cwt[t * DI + gc + 4];
          bf16x8 v = *(const bf16x8*)&xz[(size_t)(m - 3 + t) * E2 + gc];
          a8[0] += bf2f((ushort)v[0]) * a.x; a8[1] += bf2f((ushort)v[1]) * a.y;
          a8[2] += bf2f((ushort)v[2]) * a.z; a8[3] += bf2f((ushort)v[3]) * a.w;
          a8[4] += bf2f((ushort)v[4]) * b.x; a8[5] += bf2f((ushort)v[5]) * b.y;
          a8[6] += bf2f((ushort)v[6]) * b.z; a8[7] += bf2f((ushort)v[7]) * b.w;
        }
      }
      bf16x8 vo;
      #pragma unroll
      for (int j = 0; j < 8; ++j) {
        float sg = 1.f / (1.f + __expf(-a8[j]));
        vo[j] = (short)f2bf(a8[j] * sg);
      }
      *(bf16x8*)&lA[row * 64 + ((cc8 ^ (row & 7)) * 8)] = vo;
      *(bf16x8*)&xibf[(size_t)m * DI + gc] = vo;
    }
    __syncthreads();
    #pragma unroll
    for (int k2 = 0; k2 < 2; ++k2) {
      bf16x8 af[2], bf4[4];
      #pragma unroll
      for (int mi = 0; mi < 2; ++mi)
        af[mi] = *(const bf16x8*)&lA[(wr + mi * 16 + fr) * 64 + (((k2 * 4 + kg) ^ (fr & 7)) * 8)];
      #pragma unroll
      for (int ni = 0; ni < 4; ++ni)
        bf4[ni] = *(const bf16x8*)&lB[(wc + ni * 16 + fr) * 64 + (((k2 * 4 + kg) ^ (fr & 7)) * 8)];
      #pragma unroll
      for (int mi = 0; mi < 2; ++mi)
        #pragma unroll
        for (int ni = 0; ni < 4; ++ni)
          acc[mi][ni] = __builtin_amdgcn_mfma_f32_16x16x32_bf16(af[mi], bf4[ni], acc[mi][ni], 0, 0, 0);
    }
    __syncthreads();
  }
  int crow0 = tm2 + wr + kg * 4;
  int ccol0 = wc + fr;
  float* Cf = xpPart + (size_t)blockIdx.z * MROWS * 80;
  #pragma unroll
  for (int mi = 0; mi < 2; ++mi)
    #pragma unroll
    for (int ni = 0; ni < 4; ++ni) {
      int cc = ccol0 + ni * 16;
      if (cc < 80) {
        #pragma unroll
        for (int j = 0; j < 4; ++j)
          Cf[(size_t)(crow0 + mi * 16 + j) * 80 + cc] = acc[mi][ni][j];
      }
    }
}

// ---------------- combine xp split-K partials (XPZ) -> dblb f32 + dtbf bf16(padded) ----------------
__global__ __launch_bounds__(256) void k_comb_xp(const float* __restrict__ part,
    float* __restrict__ dblb, ushort* __restrict__ dtbf) {
  int i = blockIdx.x * 256 + threadIdx.x;
  if (i >= MROWS * 80) return;
  const int S = MROWS * 80;
  float s = 0.f;
  #pragma unroll
  for (int z = 0; z < XPZ; ++z) s += part[i + z * S];
  dblb[i] = s;
  int m = i / 80, c = i - m * 80;
  if (c < RR) dtbf[(size_t)m * 64 + c] = f2bf(s);
  else if (c < 64) dtbf[(size_t)m * 64 + c] = 0;
}

// ---------------- fused selective scan: 32 chunks x 8 d-lanes; grid (DI/8, BB) ----------------
__global__ __launch_bounds__(256) void k_scan_f(const float* __restrict__ delta,
    const ushort* __restrict__ ubf, const float* __restrict__ dblb,
    const ushort* __restrict__ xz, const float* __restrict__ A_log,
    const float* __restrict__ Dres, ushort* __restrict__ ybf, int layer) {
  __shared__ float shH[SDL * SSTR];
  __shared__ float shP[SDL * SSTR];
  int tid = threadIdx.x;
  int dloc = tid & (SDL - 1), chunk = tid >> 3;
  int d = blockIdx.x * SDL + dloc;
  int b = blockIdx.y;
  float an[16];
  {
    const float4* a4 = (const float4*)(A_log + ((size_t)layer * DI + d) * NS);
    #pragma unroll
    for (int q = 0; q < 4; ++q) {
      float4 v = a4[q];
      an[4*q]   = -__expf(v.x) * LOG2E; an[4*q+1] = -__expf(v.y) * LOG2E;
      an[4*q+2] = -__expf(v.z) * LOG2E; an[4*q+3] = -__expf(v.w) * LOG2E;
    }
  }
  int l0 = chunk * SLC;
  size_t rowd0 = ((size_t)b * LL + l0) * DI + d;
  size_t rowb0 = ((size_t)b * LL + l0) * 80 + RR;

  // ---- phase A: local scan; track sumD instead of per-n product ----
  float h[16];
  float sumD = 0.f;
  #pragma unroll
  for (int n = 0; n < 16; ++n) h[n] = 0.f;
  {
    size_t rd = rowd0, rb = rowb0;
    float dl = delta[rd];
    float uv = bf2f(ubf[rd]);
    float4 b0 = *(const float4*)(dblb + rb),     b1 = *(const float4*)(dblb + rb + 4);
    float4 b2 = *(const float4*)(dblb + rb + 8), b3 = *(const float4*)(dblb + rb + 12);
    for (int l = 0; l < SLC; ++l) {
      float dlc = dl, uvc = uv;
      float4 c0 = b0, c1 = b1, c2 = b2, c3 = b3;
      if (l + 1 < SLC) {
        rd += DI; rb += 80;
        dl = delta[rd]; uv = bf2f(ubf[rd]);
        b0 = *(const float4*)(dblb + rb);     b1 = *(const float4*)(dblb + rb + 4);
        b2 = *(const float4*)(dblb + rb + 8); b3 = *(const float4*)(dblb + rb + 12);
      }
      float du = dlc * uvc;
      sumD += dlc;
      float Bv[16] = { c0.x, c0.y, c0.z, c0.w, c1.x, c1.y, c1.z, c1.w,
                       c2.x, c2.y, c2.z, c2.w, c3.x, c3.y, c3.z, c3.w };
      #pragma unroll
      for (int n = 0; n < 16; ++n) {
        float a = hw_exp2(dlc * an[n]);
        h[n] = h[n] * a + du * Bv[n];
      }
    }
  }
  {
    int base = dloc * SSTR + chunk * 16;
    #pragma unroll
    for (int n = 0; n < 16; ++n) {
      shH[base + n] = h[n];
      shP[base + n] = hw_exp2(an[n] * sumD);
    }
  }
  __syncthreads();

  // ---- phase B: sequential combine across 32 chunks (8 d x 16 n = 128 threads) ----
  if (tid < SDL * 16) {
    int n2 = tid & 15, dl2 = tid >> 4;
    float hh = 0.f;
    int base = dl2 * SSTR;
    for (int c = 0; c < SCH; ++c) {
      int idx = base + c * 16 + n2;
      float t = shH[idx], p = shP[idx];
      shH[idx] = hh;
      hh = t + p * hh;
    }
  }
  __syncthreads();

  // ---- phase C: rescan from corrected h_in, fused y + gate -> bf16 ----
  {
    int base = dloc * SSTR + chunk * 16;
    #pragma unroll
    for (int n = 0; n < 16; ++n) h[n] = shH[base + n];
  }
  float dresv = Dres[(size_t)layer * DI + d];
  {
    size_t rd = rowd0, rb = rowb0;
    size_t rz = ((size_t)b * LL + l0) * E2 + DI + d;
    float dl = delta[rd];
    float uv = bf2f(ubf[rd]);
    float4 b0 = *(const float4*)(dblb + rb),      b1 = *(const float4*)(dblb + rb + 4);
    float4 b2 = *(const float4*)(dblb + rb + 8),  b3 = *(const float4*)(dblb + rb + 12);
    float4 e0 = *(const float4*)(dblb + rb + 16), e1 = *(const float4*)(dblb + rb + 20);
    float4 e2 = *(const float4*)(dblb + rb + 24), e3 = *(const float4*)(dblb + rb + 28);
    for (int l = 0; l < SLC; ++l) {
      float dlc = dl, uvc = uv;
      float4 c0 = b0, c1 = b1, c2 = b2, c3 = b3;
      float4 f0 = e0, f1 = e1, f2 = e2, f3 = e3;
      size_t rdc = rd, rzc = rz;
      if (l + 1 < SLC) {
        rd += DI; rb += 80; rz += E2;
        dl = delta[rd]; uv = bf2f(ubf[rd]);
        b0 = *(const float4*)(dblb + rb);      b1 = *(const float4*)(dblb + rb + 4);
        b2 = *(const float4*)(dblb + rb + 8);  b3 = *(const float4*)(dblb + rb + 12);
        e0 = *(const float4*)(dblb + rb + 16); e1 = *(const float4*)(dblb + rb + 20);
        e2 = *(const float4*)(dblb + rb + 24); e3 = *(const float4*)(dblb + rb + 28);
      }
      float du = dlc * uvc;
      float Bv[16] = { c0.x, c0.y, c0.z, c0.w, c1.x, c1.y, c1.z, c1.w,
                       c2.x, c2.y, c2.z, c2.w, c3.x, c3.y, c3.z, c3.w };
      float Cv[16] = { f0.x, f0.y, f0.z, f0.w, f1.x, f1.y, f1.z, f1.w,
                       f2.x, f2.y, f2.z, f2.w, f3.x, f3.y, f3.z, f3.w };
      float y = 0.f;
      #pragma unroll
      for (int n = 0; n < 16; ++n) {
        float a = hw_exp2(dlc * an[n]);
        h[n] = h[n] * a + du * Bv[n];
        y += h[n] * Cv[n];
      }
      float zv = bf2f(xz[rzc]);
      float yt = y + uvc * dresv;
      float sg = 1.f / (1.f + __expf(-zv));
      ybf[rdc] = f2bf(yt * (zv * sg));
    }
  }
}

// ---------------- final: resid += sum(hidP); out = LN(LN(resid,nf),fin) ----------------
__global__ __launch_bounds__(256) void k_final(const float* __restrict__ resid,
    const float* __restrict__ hidP,
    const float* __restrict__ nfg, const float* __restrict__ nfb,
    const float* __restrict__ fig, const float* __restrict__ fib,
    float* __restrict__ out) {
  __shared__ float red[4];
  int m = blockIdx.x, t = threadIdx.x;
  size_t base = (size_t)m * DD;
  float x0 = resid[base + t], x1 = resid[base + t + 256], x2 = resid[base + t + 512];
  #pragma unroll
  for (int z = 0; z < OZ; ++z) {
    size_t bz = (size_t)z * MROWS * DD + base;
    x0 += hidP[bz + t]; x1 += hidP[bz + t + 256]; x2 += hidP[bz + t + 512];
  }
  float S  = block_sum(x0 + x1 + x2, red);
  float S2 = block_sum(x0*x0 + x1*x1 + x2*x2, red);
  float mu = S * (1.f / DD);
  float var = S2 * (1.f / DD) - mu * mu;
  float rs = rsqrtf(var + EPSV);
  float t0 = (x0 - mu) * rs * nfg[t]       + nfb[t];
  float t1 = (x1 - mu) * rs * nfg[t + 256] + nfb[t + 256];
  float t2 = (x2 - mu) * rs * nfg[t + 512] + nfb[t + 512];
  S  = block_sum(t0 + t1 + t2, red);
  S2 = block_sum(t0*t0 + t1*t1 + t2*t2, red);
  mu = S * (1.f / DD);
  var = S2 * (1.f / DD) - mu * mu;
  rs = rsqrtf(var + EPSV);
  out[base + t]       = (t0 - mu) * rs * fig[t]       + fib[t];
  out[base + t + 256] = (t1 - mu) * rs * fig[t + 256] + fib[t + 256];
  out[base + t + 512] = (t2 - mu) * rs * fig[t + 512] + fib[t + 512];
}

extern "C" void kernel_launch(void* const* d_in, const int* in_sizes, int n_in,
                              void* d_out, int out_size, void* d_ws, size_t ws_size,
                              hipStream_t stream) {
  const int*   ids    = (const int*)  d_in[0];
  const float* wte    = (const float*)d_in[1];
  const float* wpe    = (const float*)d_in[2];
  const float* ln_g   = (const float*)d_in[3];
  const float* ln_b   = (const float*)d_in[4];
  const float* in_W   = (const float*)d_in[5];
  const float* conv_W = (const float*)d_in[6];
  const float* conv_b = (const float*)d_in[7];
  const float* xp_W   = (const float*)d_in[8];
  const float* dt_W   = (const float*)d_in[9];
  const float* dt_b   = (const float*)d_in[10];
  const float* A_log  = (const float*)d_in[11];
  const float* Dres   = (const float*)d_in[12];
  const float* out_W  = (const float*)d_in[13];
  const float* nf_g   = (const float*)d_in[14];
  const float* nf_b   = (const float*)d_in[15];
  const float* fin_g  = (const float*)d_in[16];
  const float* fin_b  = (const float*)d_in[17];

  char* p = (char*)d_ws;
  auto take = [&](size_t bytes) {
    char* r = p; p += (bytes + 255) & ~(size_t)255; return r;
  };
  float*  resid  = (float*) take((size_t)MROWS * DD * 4);
  float*  hidP   = (float*) take((size_t)OZ * MROWS * DD * 4);
  ushort* h_bf   = (ushort*)take((size_t)MROWS * DD * 2);
  ushort* xz     = (ushort*)take((size_t)MROWS * E2 * 2);
  ushort* xibf   = (ushort*)take((size_t)MROWS * DI * 2);
  float*  xpPart = (float*) take((size_t)XPZ * MROWS * 80 * 4);
  float*  dblb   = (float*) take((size_t)MROWS * 80 * 4);
  ushort* dtbf   = (ushort*)take((size_t)MROWS * 64 * 2);
  float*  delta  = (float*) take((size_t)MROWS * DI * 4);
  ushort* ybf    = (ushort*)take((size_t)MROWS * DI * 2);
  ushort* wInBf  = (ushort*)take((size_t)NLAYER * E2 * DD * 2);
  ushort* wXpBf  = (ushort*)take((size_t)NLAYER * 80 * DI * 2);
  ushort* wDtBf  = (ushort*)take((size_t)NLAYER * DI * 64 * 2);
  ushort* wOutBf = (ushort*)take((size_t)NLAYER * DD * DI * 2);
  float*  convWt = (float*) take((size_t)NLAYER * 4 * DI * 4);

  {
    int total = NLAYER * E2 * DD / 4 + NLAYER * DD * DI / 4;
    k_cvtA<<<(total + 255) / 256, 256, 0, stream>>>(in_W, out_W, wInBf, wOutBf);
  }
  {
    int total = NLAYER * 80 * DI / 4 + NLAYER * DI * 64 + NLAYER * DI * 4;
    k_cvtB<<<(total + 255) / 256, 256, 0, stream>>>(xp_W, dt_W, conv_W,
                                                    wXpBf, wDtBf, convWt);
  }
  k_embed<<<(MROWS * (DD / 4) + 255) / 256, 256, 0, stream>>>(ids, wte, wpe, resid);

  for (int i = 0; i < NLAYER; ++i) {
    k_ln<<<MROWS, 256, 0, stream>>>(hidP, resid,
                                    ln_g + (size_t)i * DD, ln_b + (size_t)i * DD,
                                    h_bf, i > 0 ? 1 : 0);

    { dim3 g(E2 / 128, MROWS / 64, 1);    // 24 x 32 = 768 blocks
      k_gemm64<1, 128><<<g, 256, 0, stream>>>(h_bf, wInBf + (size_t)i * E2 * DD,
                                              (void*)xz, nullptr, E2, DD, DD / 64); }

    { dim3 g(1, MROWS / 64, XPZ);         // 32 x 12 = 384 blocks, 2 K-steps
      k_xpconv<<<g, 256, 0, stream>>>(xz, wXpBf + (size_t)i * 80 * DI,
                                      convWt + (size_t)i * 4 * DI,
                                      conv_b + (size_t)i * DI, xibf, xpPart); }

    k_comb_xp<<<(MROWS * 80 + 255) / 256, 256, 0, stream>>>(xpPart, dblb, dtbf);

    { dim3 g(DI / 64, MROWS / 64, 1);     // 24 x 32 = 768 blocks, K=64
      k_gemm64<2, 64><<<g, 256, 0, stream>>>(dtbf, wDtBf + (size_t)i * DI * 64,
                                             (void*)delta, dt_b + (size_t)i * DI, DI, 64, 1); }

    { dim3 g(DI / SDL, BB);               // 192 x 4 = 768 blocks
      k_scan_f<<<g, 256, 0, stream>>>(delta, xibf, dblb, xz, A_log, Dres, ybf, i); }

    { dim3 g(DD / 128, MROWS / 64, OZ);   // 6 x 32 x 2 = 384 blocks, 12 stages
      k_gemm64<0, 128><<<g, 256, 0, stream>>>(ybf, wOutBf + (size_t)i * DD * DI,
                                              (void*)hidP, nullptr, DD, DI, DI / 64 / OZ); }
  }

  k_final<<<MROWS, 256, 0, stream>>>(resid, hidP, nf_g, nf_b,
                                     fin_g, fin_b, (float*)d_out);
}

// Round 13
// 1352.902 us; speedup vs baseline: 1.0542x; 1.0542x over previous
//
#include <hip/hip_runtime.h>

#define BB 4
#define LL 512
#define DD 768
#define NLAYER 12
#define DI 1536
#define NS 16
#define KC 4
#define RR 48
#define MROWS (BB*LL)   // 2048
#define E2 (2*DI)       // 3072
#define EPSV 1e-5f
#define LOG2E 1.4426950408889634f
#define XPZ 12          // xp split-K factor (2 K-steps each)
#define OZ 2            // out-proj split-K factor
// scan geometry (R10-proven): 16 chunks x 16 d-lanes per block
#define CH2 16
#define LC2 (LL/CH2)    // 32

typedef __attribute__((ext_vector_type(8))) short bf16x8;
typedef __attribute__((ext_vector_type(4))) float f32x4;

#define GLL16(g, l) __builtin_amdgcn_global_load_lds( \
    (const __attribute__((address_space(1))) void*)(g), \
    (__attribute__((address_space(3))) void*)(l), 16, 0, 0)

__device__ inline float hw_exp2(float x) { return __builtin_amdgcn_exp2f(x); }

__device__ inline ushort f2bf(float f) {
  union { float f; unsigned u; } v; v.f = f;
  unsigned u = v.u;
  unsigned r = (u + 0x7fffu + ((u >> 16) & 1u)) >> 16;
  return (ushort)r;
}
__device__ inline float bf2f(ushort u) {
  union { unsigned u; float f; } v; v.u = ((unsigned)u) << 16; return v.f;
}

__device__ inline float block_sum(float v, volatile float* red) {
  #pragma unroll
  for (int o = 32; o > 0; o >>= 1) v += __shfl_down(v, o);
  if ((threadIdx.x & 63) == 0) red[threadIdx.x >> 6] = v;
  __syncthreads();
  float t = red[0] + red[1] + red[2] + red[3];
  __syncthreads();
  return t;
}

// ---------------- cvtA: in_W + out_W f32->bf16 ----------------
__global__ __launch_bounds__(256) void k_cvtA(const float* __restrict__ inW,
    const float* __restrict__ outW, ushort* __restrict__ wIn,
    ushort* __restrict__ wOut) {
  int i = blockIdx.x * 256 + threadIdx.x;
  const int nIn = NLAYER * E2 * DD / 4;
  const int nOut = NLAYER * DD * DI / 4;
  if (i < nIn) {
    float4 v = ((const float4*)inW)[i];
    ushort4 o = { f2bf(v.x), f2bf(v.y), f2bf(v.z), f2bf(v.w) };
    ((ushort4*)wIn)[i] = o;
  } else if (i < nIn + nOut) {
    int j = i - nIn;
    float4 v = ((const float4*)outW)[j];
    ushort4 o = { f2bf(v.x), f2bf(v.y), f2bf(v.z), f2bf(v.w) };
    ((ushort4*)wOut)[j] = o;
  }
}

// ---------------- cvtB: xp_W bf16; dt_W bf16 64-pad; conv_W transpose ----------------
__global__ __launch_bounds__(256) void k_cvtB(const float* __restrict__ xpW,
    const float* __restrict__ dtW, const float* __restrict__ convW,
    ushort* __restrict__ wXp, ushort* __restrict__ wDt, float* __restrict__ convWt) {
  int i = blockIdx.x * 256 + threadIdx.x;
  const int n0 = NLAYER * 80 * DI / 4;
  const int n1 = NLAYER * DI * 64;
  const int n2 = NLAYER * DI * 4;
  if (i < n0) {
    float4 v = ((const float4*)xpW)[i];
    ushort4 o = { f2bf(v.x), f2bf(v.y), f2bf(v.z), f2bf(v.w) };
    ((ushort4*)wXp)[i] = o;
  } else if (i < n0 + n1) {
    int j = i - n0;
    int r = j >> 6, c = j & 63;
    wDt[j] = (c < RR) ? f2bf(dtW[(size_t)r * RR + c]) : (ushort)0;
  } else if (i < n0 + n1 + n2) {
    int j = i - n0 - n1;
    int l = j / (DI * 4);
    int rem = j - l * (DI * 4);
    int d = rem >> 2, k = rem & 3;
    convWt[(size_t)l * 4 * DI + k * DI + d] = convW[(size_t)l * DI * 4 + d * 4 + k];
  }
}

// ---------------- embedding: resid = wte[ids] + wpe ----------------
__global__ __launch_bounds__(256) void k_embed(const int* __restrict__ ids,
    const float* __restrict__ wte, const float* __restrict__ wpe,
    float* __restrict__ resid) {
  const int nd4 = DD / 4;
  int i = blockIdx.x * 256 + threadIdx.x;
  if (i >= MROWS * nd4) return;
  int m = i / nd4, d4 = i - m * nd4;
  int l = m & (LL - 1);
  int tok = ids[m];
  float4 a = ((const float4*)wte)[(size_t)tok * nd4 + d4];
  float4 b = ((const float4*)wpe)[(size_t)l * nd4 + d4];
  float4 o; o.x = a.x + b.x; o.y = a.y + b.y; o.z = a.z + b.z; o.w = a.w + b.w;
  ((float4*)resid)[i] = o;
}

// ---------------- fused residual add (OZ partials) + layernorm -> bf16 ----------------
__global__ __launch_bounds__(256) void k_ln(const float* __restrict__ hidP,
    float* __restrict__ resid, const float* __restrict__ g, const float* __restrict__ b,
    ushort* __restrict__ hbf, int addHidden) {
  __shared__ float red[4];
  int m = blockIdx.x, t = threadIdx.x;
  size_t base = (size_t)m * DD;
  float x0 = resid[base + t], x1 = resid[base + t + 256], x2 = resid[base + t + 512];
  if (addHidden) {
    #pragma unroll
    for (int z = 0; z < OZ; ++z) {
      size_t bz = (size_t)z * MROWS * DD + base;
      x0 += hidP[bz + t]; x1 += hidP[bz + t + 256]; x2 += hidP[bz + t + 512];
    }
    resid[base + t] = x0; resid[base + t + 256] = x1; resid[base + t + 512] = x2;
  }
  float S  = block_sum(x0 + x1 + x2, red);
  float S2 = block_sum(x0*x0 + x1*x1 + x2*x2, red);
  float mu = S * (1.f / DD);
  float var = S2 * (1.f / DD) - mu * mu;
  float rs = rsqrtf(var + EPSV);
  hbf[base + t]       = f2bf((x0 - mu) * rs * g[t]       + b[t]);
  hbf[base + t + 256] = f2bf((x1 - mu) * rs * g[t + 256] + b[t + 256]);
  hbf[base + t + 512] = f2bf((x2 - mu) * rs * g[t + 512] + b[t + 512]);
}

// ---------------- 64x128 (MxN) MFMA GEMM, BK=64, NT, bf16 in ----------------
// OM=0: f32 partials (z-offset). OM=1: bf16. OM=2: bf16 softplus(acc + dtb[col]).
template<int OM>
__global__ __launch_bounds__(256) void k_gemm64(const ushort* __restrict__ A,
    const ushort* __restrict__ Bw, void* __restrict__ Cv, const float* __restrict__ dtb,
    int N, int K, int kSteps) {
  __shared__ ushort lA[64 * 64];
  __shared__ ushort lB[128 * 64];
  int tid = threadIdx.x;
  int wid = tid >> 6, lane = tid & 63;
  int tm = blockIdx.y * 64, tn = blockIdx.x * 128;
  int kBase = blockIdx.z * kSteps * 64;
  int wr = (wid >> 1) * 32, wc = (wid & 1) * 64;
  int fr = lane & 15, kg = lane >> 4;
  int sR = lane >> 3;
  int sC = ((lane & 7) ^ sR) * 8;
  f32x4 acc[2][4];
  #pragma unroll
  for (int mi = 0; mi < 2; ++mi)
    #pragma unroll
    for (int ni = 0; ni < 4; ++ni)
      acc[mi][ni] = {0.f, 0.f, 0.f, 0.f};

  for (int ks = 0; ks < kSteps; ++ks) {
    int k0 = kBase + ks * 64;
    #pragma unroll
    for (int i = 0; i < 2; ++i) {
      int r0 = wid * 16 + i * 8;
      GLL16(A + (size_t)(tm + r0 + sR) * K + k0 + sC, &lA[r0 * 64]);
    }
    #pragma unroll
    for (int i = 0; i < 4; ++i) {
      int r0 = wid * 32 + i * 8;
      int brow = tn + r0 + sR;
      if (brow > N - 1) brow = N - 1;
      GLL16(Bw + (size_t)brow * K + k0 + sC, &lB[r0 * 64]);
    }
    __syncthreads();
    #pragma unroll
    for (int k2 = 0; k2 < 2; ++k2) {
      bf16x8 af[2], bfr[4];
      #pragma unroll
      for (int mi = 0; mi < 2; ++mi)
        af[mi] = *(const bf16x8*)&lA[(wr + mi * 16 + fr) * 64 + (((k2 * 4 + kg) ^ (fr & 7)) * 8)];
      #pragma unroll
      for (int ni = 0; ni < 4; ++ni)
        bfr[ni] = *(const bf16x8*)&lB[(wc + ni * 16 + fr) * 64 + (((k2 * 4 + kg) ^ (fr & 7)) * 8)];
      #pragma unroll
      for (int mi = 0; mi < 2; ++mi)
        #pragma unroll
        for (int ni = 0; ni < 4; ++ni)
          acc[mi][ni] = __builtin_amdgcn_mfma_f32_16x16x32_bf16(af[mi], bfr[ni], acc[mi][ni], 0, 0, 0);
    }
    __syncthreads();
  }
  int crow0 = tm + wr + kg * 4;
  int ccol0 = tn + wc + fr;
  if (OM == 0) {
    float* C = (float*)Cv + (size_t)blockIdx.z * ((size_t)gridDim.y * 64) * N;
    #pragma unroll
    for (int mi = 0; mi < 2; ++mi)
      #pragma unroll
      for (int ni = 0; ni < 4; ++ni) {
        int cc = ccol0 + ni * 16;
        if (cc < N) {
          #pragma unroll
          for (int j = 0; j < 4; ++j)
            C[(size_t)(crow0 + mi * 16 + j) * N + cc] = acc[mi][ni][j];
        }
      }
  } else if (OM == 1) {
    ushort* C = (ushort*)Cv;
    #pragma unroll
    for (int mi = 0; mi < 2; ++mi)
      #pragma unroll
      for (int ni = 0; ni < 4; ++ni) {
        int cc = ccol0 + ni * 16;
        if (cc < N) {
          #pragma unroll
          for (int j = 0; j < 4; ++j)
            C[(size_t)(crow0 + mi * 16 + j) * N + cc] = f2bf(acc[mi][ni][j]);
        }
      }
  } else {
    ushort* C = (ushort*)Cv;
    #pragma unroll
    for (int mi = 0; mi < 2; ++mi)
      #pragma unroll
      for (int ni = 0; ni < 4; ++ni) {
        int cc = ccol0 + ni * 16;
        if (cc < N) {
          float bv = dtb[cc];
          #pragma unroll
          for (int j = 0; j < 4; ++j) {
            float x = acc[mi][ni][j] + bv;
            float sp = (x > 20.f) ? x : log1pf(__expf(x));
            C[(size_t)(crow0 + mi * 16 + j) * N + cc] = f2bf(sp);
          }
        }
      }
  }
}

// ---------------- conv-fused xp GEMM (64-row, 2 K-steps/z): conv+silu in A-staging ----------------
// grid (1, MROWS/64, XPZ); z owns 128 channels.
__global__ __launch_bounds__(256) void k_xpconv(const ushort* __restrict__ xz,
    const ushort* __restrict__ wXpL, const float* __restrict__ cwt,
    const float* __restrict__ cbl, ushort* __restrict__ xibf,
    float* __restrict__ xpPart) {
  __shared__ ushort lA[64 * 64];
  __shared__ ushort lB[128 * 64];
  int tid = threadIdx.x;
  int wid = tid >> 6, lane = tid & 63;
  int tm2 = blockIdx.y * 64;
  int kBase = blockIdx.z * 128;
  int wr = (wid >> 1) * 32, wc = (wid & 1) * 64;
  int fr = lane & 15, kg = lane >> 4;
  int sR = lane >> 3, sC = ((lane & 7) ^ sR) * 8;
  f32x4 acc[2][4];
  #pragma unroll
  for (int mi = 0; mi < 2; ++mi)
    #pragma unroll
    for (int ni = 0; ni < 4; ++ni)
      acc[mi][ni] = {0.f, 0.f, 0.f, 0.f};
  for (int ks = 0; ks < 2; ++ks) {
    int k0 = kBase + ks * 64;
    #pragma unroll
    for (int i2 = 0; i2 < 4; ++i2) {
      int r0 = wid * 32 + i2 * 8;
      int brow = r0 + sR;
      if (brow > 79) brow = 79;
      GLL16(wXpL + (size_t)brow * DI + k0 + sC, &lB[r0 * 64]);
    }
    #pragma unroll
    for (int c2 = 0; c2 < 2; ++c2) {
      int chunk = tid + c2 * 256;
      int row = chunk >> 3, cc8 = chunk & 7;
      int m = tm2 + row, l = m & (LL - 1);
      int gc = k0 + cc8 * 8;
      float a8[8];
      {
        float4 a = *(const float4*)&cbl[gc];
        float4 b = *(const float4*)&cbl[gc + 4];
        a8[0] = a.x; a8[1] = a.y; a8[2] = a.z; a8[3] = a.w;
        a8[4] = b.x; a8[5] = b.y; a8[6] = b.z; a8[7] = b.w;
      }
      #pragma unroll
      for (int t = 0; t < 4; ++t) {
        if (l - 3 + t >= 0) {
          float4 a = *(const float4*)&cwt[t * DI + gc];
          float4 b = *(const float4*)&cwt[t * DI + gc + 4];
          bf16x8 v = *(const bf16x8*)&xz[(size_t)(m - 3 + t) * E2 + gc];
          a8[0] += bf2f((ushort)v[0]) * a.x; a8[1] += bf2f((ushort)v[1]) * a.y;
          a8[2] += bf2f((ushort)v[2]) * a.z; a8[3] += bf2f((ushort)v[3]) * a.w;
          a8[4] += bf2f((ushort)v[4]) * b.x; a8[5] += bf2f((ushort)v[5]) * b.y;
          a8[6] += bf2f((ushort)v[6]) * b.z; a8[7] += bf2f((ushort)v[7]) * b.w;
        }
      }
      bf16x8 vo;
      #pragma unroll
      for (int j = 0; j < 8; ++j) {
        float sg = 1.f / (1.f + __expf(-a8[j]));
        vo[j] = (short)f2bf(a8[j] * sg);
      }
      *(bf16x8*)&lA[row * 64 + ((cc8 ^ (row & 7)) * 8)] = vo;
      *(bf16x8*)&xibf[(size_t)m * DI + gc] = vo;
    }
    __syncthreads();
    #pragma unroll
    for (int k2 = 0; k2 < 2; ++k2) {
      bf16x8 af[2], bf4[4];
      #pragma unroll
      for (int mi = 0; mi < 2; ++mi)
        af[mi] = *(const bf16x8*)&lA[(wr + mi * 16 + fr) * 64 + (((k2 * 4 + kg) ^ (fr & 7)) * 8)];
      #pragma unroll
      for (int ni = 0; ni < 4; ++ni)
        bf4[ni] = *(const bf16x8*)&lB[(wc + ni * 16 + fr) * 64 + (((k2 * 4 + kg) ^ (fr & 7)) * 8)];
      #pragma unroll
      for (int mi = 0; mi < 2; ++mi)
        #pragma unroll
        for (int ni = 0; ni < 4; ++ni)
          acc[mi][ni] = __builtin_amdgcn_mfma_f32_16x16x32_bf16(af[mi], bf4[ni], acc[mi][ni], 0, 0, 0);
    }
    __syncthreads();
  }
  int crow0 = tm2 + wr + kg * 4;
  int ccol0 = wc + fr;
  float* Cf = xpPart + (size_t)blockIdx.z * MROWS * 80;
  #pragma unroll
  for (int mi = 0; mi < 2; ++mi)
    #pragma unroll
    for (int ni = 0; ni < 4; ++ni) {
      int cc = ccol0 + ni * 16;
      if (cc < 80) {
        #pragma unroll
        for (int j = 0; j < 4; ++j)
          Cf[(size_t)(crow0 + mi * 16 + j) * 80 + cc] = acc[mi][ni][j];
      }
    }
}

// ---------------- combine xp split-K partials (XPZ) -> dblb f32 + dtbf bf16(padded) ----------------
__global__ __launch_bounds__(256) void k_comb_xp(const float* __restrict__ part,
    float* __restrict__ dblb, ushort* __restrict__ dtbf) {
  int i = blockIdx.x * 256 + threadIdx.x;
  if (i >= MROWS * 80) return;
  const int S = MROWS * 80;
  float s = 0.f;
  #pragma unroll
  for (int z = 0; z < XPZ; ++z) s += part[i + z * S];
  dblb[i] = s;
  int m = i / 80, c = i - m * 80;
  if (c < RR) dtbf[(size_t)m * 64 + c] = f2bf(s);
  else if (c < 64) dtbf[(size_t)m * 64 + c] = 0;
}

// ---------------- fused selective scan: 16 chunks x 16 d-lanes; grid (DI/16, BB) ----------------
__global__ __launch_bounds__(256) void k_scan_f(const ushort* __restrict__ delta,
    const ushort* __restrict__ ubf, const float* __restrict__ dblb,
    const ushort* __restrict__ xz, const float* __restrict__ A_log,
    const float* __restrict__ Dres, ushort* __restrict__ ybf, int layer) {
  __shared__ float shH[16 * 257];
  __shared__ float shP[16 * 257];
  int tid = threadIdx.x;
  int dloc = tid & 15, chunk = tid >> 4;
  int d = blockIdx.x * 16 + dloc;
  int b = blockIdx.y;
  float an[16];
  {
    const float4* a4 = (const float4*)(A_log + ((size_t)layer * DI + d) * NS);
    #pragma unroll
    for (int q = 0; q < 4; ++q) {
      float4 v = a4[q];
      an[4*q]   = -__expf(v.x) * LOG2E; an[4*q+1] = -__expf(v.y) * LOG2E;
      an[4*q+2] = -__expf(v.z) * LOG2E; an[4*q+3] = -__expf(v.w) * LOG2E;
    }
  }
  int l0 = chunk * LC2;
  size_t rowd0 = ((size_t)b * LL + l0) * DI + d;
  size_t rowb0 = ((size_t)b * LL + l0) * 80 + RR;

  // ---- phase A: local scan; sumD replaces per-n product chain ----
  float h[16];
  float sumD = 0.f;
  #pragma unroll
  for (int n = 0; n < 16; ++n) h[n] = 0.f;
  {
    size_t rd = rowd0, rb = rowb0;
    float dl = bf2f(delta[rd]);
    float uv = bf2f(ubf[rd]);
    float4 b0 = *(const float4*)(dblb + rb),     b1 = *(const float4*)(dblb + rb + 4);
    float4 b2 = *(const float4*)(dblb + rb + 8), b3 = *(const float4*)(dblb + rb + 12);
    for (int l = 0; l < LC2; ++l) {
      float dlc = dl, uvc = uv;
      float4 c0 = b0, c1 = b1, c2 = b2, c3 = b3;
      if (l + 1 < LC2) {
        rd += DI; rb += 80;
        dl = bf2f(delta[rd]); uv = bf2f(ubf[rd]);
        b0 = *(const float4*)(dblb + rb);     b1 = *(const float4*)(dblb + rb + 4);
        b2 = *(const float4*)(dblb + rb + 8); b3 = *(const float4*)(dblb + rb + 12);
      }
      float du = dlc * uvc;
      sumD += dlc;
      float Bv[16] = { c0.x, c0.y, c0.z, c0.w, c1.x, c1.y, c1.z, c1.w,
                       c2.x, c2.y, c2.z, c2.w, c3.x, c3.y, c3.z, c3.w };
      #pragma unroll
      for (int n = 0; n < 16; ++n) {
        float a = hw_exp2(dlc * an[n]);
        h[n] = h[n] * a + du * Bv[n];
      }
    }
  }
  {
    int base = dloc * 257 + chunk * 16;
    #pragma unroll
    for (int n = 0; n < 16; ++n) {
      shH[base + n] = h[n];
      shP[base + n] = hw_exp2(an[n] * sumD);
    }
  }
  __syncthreads();

  // ---- phase B: sequential combine across chunks (16 d x 16 n = 256 threads) ----
  {
    int n2 = tid & 15, dl2 = tid >> 4;
    float hh = 0.f;
    int base = dl2 * 257;
    for (int c = 0; c < CH2; ++c) {
      int idx = base + c * 16 + n2;
      float t = shH[idx], p = shP[idx];
      shH[idx] = hh;
      hh = t + p * hh;
    }
  }
  __syncthreads();

  // ---- phase C: rescan from corrected h_in, fused y + gate -> bf16 ----
  {
    int base = dloc * 257 + chunk * 16;
    #pragma unroll
    for (int n = 0; n < 16; ++n) h[n] = shH[base + n];
  }
  float dresv = Dres[(size_t)layer * DI + d];
  {
    size_t rd = rowd0, rb = rowb0;
    size_t rz = ((size_t)b * LL + l0) * E2 + DI + d;
    float dl = bf2f(delta[rd]);
    float uv = bf2f(ubf[rd]);
    float4 b0 = *(const float4*)(dblb + rb),      b1 = *(const float4*)(dblb + rb + 4);
    float4 b2 = *(const float4*)(dblb + rb + 8),  b3 = *(const float4*)(dblb + rb + 12);
    float4 e0 = *(const float4*)(dblb + rb + 16), e1 = *(const float4*)(dblb + rb + 20);
    float4 e2 = *(const float4*)(dblb + rb + 24), e3 = *(const float4*)(dblb + rb + 28);
    for (int l = 0; l < LC2; ++l) {
      float dlc = dl, uvc = uv;
      float4 c0 = b0, c1 = b1, c2 = b2, c3 = b3;
      float4 f0 = e0, f1 = e1, f2 = e2, f3 = e3;
      size_t rdc = rd, rzc = rz;
      if (l + 1 < LC2) {
        rd += DI; rb += 80; rz += E2;
        dl = bf2f(delta[rd]); uv = bf2f(ubf[rd]);
        b0 = *(const float4*)(dblb + rb);      b1 = *(const float4*)(dblb + rb + 4);
        b2 = *(const float4*)(dblb + rb + 8);  b3 = *(const float4*)(dblb + rb + 12);
        e0 = *(const float4*)(dblb + rb + 16); e1 = *(const float4*)(dblb + rb + 20);
        e2 = *(const float4*)(dblb + rb + 24); e3 = *(const float4*)(dblb + rb + 28);
      }
      float du = dlc * uvc;
      float Bv[16] = { c0.x, c0.y, c0.z, c0.w, c1.x, c1.y, c1.z, c1.w,
                       c2.x, c2.y, c2.z, c2.w, c3.x, c3.y, c3.z, c3.w };
      float Cv[16] = { f0.x, f0.y, f0.z, f0.w, f1.x, f1.y, f1.z, f1.w,
                       f2.x, f2.y, f2.z, f2.w, f3.x, f3.y, f3.z, f3.w };
      float y = 0.f;
      #pragma unroll
      for (int n = 0; n < 16; ++n) {
        float a = hw_exp2(dlc * an[n]);
        h[n] = h[n] * a + du * Bv[n];
        y += h[n] * Cv[n];
      }
      float zv = bf2f(xz[rzc]);
      float yt = y + uvc * dresv;
      float sg = 1.f / (1.f + __expf(-zv));
      ybf[rdc] = f2bf(yt * (zv * sg));
    }
  }
}

// ---------------- final: resid += sum(hidP); out = LN(LN(resid,nf),fin) ----------------
__global__ __launch_bounds__(256) void k_final(const float* __restrict__ resid,
    const float* __restrict__ hidP,
    const float* __restrict__ nfg, const float* __restrict__ nfb,
    const float* __restrict__ fig, const float* __restrict__ fib,
    float* __restrict__ out) {
  __shared__ float red[4];
  int m = blockIdx.x, t = threadIdx.x;
  size_t base = (size_t)m * DD;
  float x0 = resid[base + t], x1 = resid[base + t + 256], x2 = resid[base + t + 512];
  #pragma unroll
  for (int z = 0; z < OZ; ++z) {
    size_t bz = (size_t)z * MROWS * DD + base;
    x0 += hidP[bz + t]; x1 += hidP[bz + t + 256]; x2 += hidP[bz + t + 512];
  }
  float S  = block_sum(x0 + x1 + x2, red);
  float S2 = block_sum(x0*x0 + x1*x1 + x2*x2, red);
  float mu = S * (1.f / DD);
  float var = S2 * (1.f / DD) - mu * mu;
  float rs = rsqrtf(var + EPSV);
  float t0 = (x0 - mu) * rs * nfg[t]       + nfb[t];
  float t1 = (x1 - mu) * rs * nfg[t + 256] + nfb[t + 256];
  float t2 = (x2 - mu) * rs * nfg[t + 512] + nfb[t + 512];
  S  = block_sum(t0 + t1 + t2, red);
  S2 = block_sum(t0*t0 + t1*t1 + t2*t2, red);
  mu = S * (1.f / DD);
  var = S2 * (1.f / DD) - mu * mu;
  rs = rsqrtf(var + EPSV);
  out[base + t]       = (t0 - mu) * rs * fig[t]       + fib[t];
  out[base + t + 256] = (t1 - mu) * rs * fig[t + 256] + fib[t + 256];
  out[base + t + 512] = (t2 - mu) * rs * fig[t + 512] + fib[t + 512];
}

extern "C" void kernel_launch(void* const* d_in, const int* in_sizes, int n_in,
                              void* d_out, int out_size, void* d_ws, size_t ws_size,
                              hipStream_t stream) {
  const int*   ids    = (const int*)  d_in[0];
  const float* wte    = (const float*)d_in[1];
  const float* wpe    = (const float*)d_in[2];
  const float* ln_g   = (const float*)d_in[3];
  const float* ln_b   = (const float*)d_in[4];
  const float* in_W   = (const float*)d_in[5];
  const float* conv_W = (const float*)d_in[6];
  const float* conv_b = (const float*)d_in[7];
  const float* xp_W   = (const float*)d_in[8];
  const float* dt_W   = (const float*)d_in[9];
  const float* dt_b   = (const float*)d_in[10];
  const float* A_log  = (const float*)d_in[11];
  const float* Dres   = (const float*)d_in[12];
  const float* out_W  = (const float*)d_in[13];
  const float* nf_g   = (const float*)d_in[14];
  const float* nf_b   = (const float*)d_in[15];
  const float* fin_g  = (const float*)d_in[16];
  const float* fin_b  = (const float*)d_in[17];

  char* p = (char*)d_ws;
  auto take = [&](size_t bytes) {
    char* r = p; p += (bytes + 255) & ~(size_t)255; return r;
  };
  float*  resid  = (float*) take((size_t)MROWS * DD * 4);
  float*  hidP   = (float*) take((size_t)OZ * MROWS * DD * 4);
  ushort* h_bf   = (ushort*)take((size_t)MROWS * DD * 2);
  ushort* xz     = (ushort*)take((size_t)MROWS * E2 * 2);
  ushort* xibf   = (ushort*)take((size_t)MROWS * DI * 2);
  float*  xpPart = (float*) take((size_t)XPZ * MROWS * 80 * 4);
  float*  dblb   = (float*) take((size_t)MROWS * 80 * 4);
  ushort* dtbf   = (ushort*)take((size_t)MROWS * 64 * 2);
  ushort* delta  = (ushort*)take((size_t)MROWS * DI * 2);
  ushort* ybf    = (ushort*)take((size_t)MROWS * DI * 2);
  ushort* wInBf  = (ushort*)take((size_t)NLAYER * E2 * DD * 2);
  ushort* wXpBf  = (ushort*)take((size_t)NLAYER * 80 * DI * 2);
  ushort* wDtBf  = (ushort*)take((size_t)NLAYER * DI * 64 * 2);
  ushort* wOutBf = (ushort*)take((size_t)NLAYER * DD * DI * 2);
  float*  convWt = (float*) take((size_t)NLAYER * 4 * DI * 4);

  {
    int total = NLAYER * E2 * DD / 4 + NLAYER * DD * DI / 4;
    k_cvtA<<<(total + 255) / 256, 256, 0, stream>>>(in_W, out_W, wInBf, wOutBf);
  }
  {
    int total = NLAYER * 80 * DI / 4 + NLAYER * DI * 64 + NLAYER * DI * 4;
    k_cvtB<<<(total + 255) / 256, 256, 0, stream>>>(xp_W, dt_W, conv_W,
                                                    wXpBf, wDtBf, convWt);
  }
  k_embed<<<(MROWS * (DD / 4) + 255) / 256, 256, 0, stream>>>(ids, wte, wpe, resid);

  for (int i = 0; i < NLAYER; ++i) {
    k_ln<<<MROWS, 256, 0, stream>>>(hidP, resid,
                                    ln_g + (size_t)i * DD, ln_b + (size_t)i * DD,
                                    h_bf, i > 0 ? 1 : 0);

    { dim3 g(E2 / 128, MROWS / 64, 1);    // 24 x 32 = 768 blocks
      k_gemm64<1><<<g, 256, 0, stream>>>(h_bf, wInBf + (size_t)i * E2 * DD,
                                         (void*)xz, nullptr, E2, DD, DD / 64); }

    { dim3 g(1, MROWS / 64, XPZ);         // 32 x 12 = 384 blocks, 2 K-steps
      k_xpconv<<<g, 256, 0, stream>>>(xz, wXpBf + (size_t)i * 80 * DI,
                                      convWt + (size_t)i * 4 * DI,
                                      conv_b + (size_t)i * DI, xibf, xpPart); }

    k_comb_xp<<<(MROWS * 80 + 255) / 256, 256, 0, stream>>>(xpPart, dblb, dtbf);

    { dim3 g(DI / 128, MROWS / 64, 1);    // 12 x 32 = 384 blocks, K=64
      k_gemm64<2><<<g, 256, 0, stream>>>(dtbf, wDtBf + (size_t)i * DI * 64,
                                         (void*)delta, dt_b + (size_t)i * DI, DI, 64, 1); }

    { dim3 g(DI / 16, BB);                // 96 x 4 = 384 blocks
      k_scan_f<<<g, 256, 0, stream>>>(delta, xibf, dblb, xz, A_log, Dres, ybf, i); }

    { dim3 g(DD / 128, MROWS / 64, OZ);   // 6 x 32 x 2 = 384 blocks, 12 stages
      k_gemm64<0><<<g, 256, 0, stream>>>(ybf, wOutBf + (size_t)i * DD * DI,
                                         (void*)hidP, nullptr, DD, DI, DI / 64 / OZ); }
  }

  k_final<<<MROWS, 256, 0, stream>>>(resid, hidP, nf_g, nf_b,
                                     fin_g, fin_b, (float*)d_out);
}

// Round 14
// 1341.264 us; speedup vs baseline: 1.0634x; 1.0087x over previous
//
#include <hip/hip_runtime.h>

#define BB 4
#define LL 512
#define DD 768
#define NLAYER 12
#define DI 1536
#define NS 16
#define KC 4
#define RR 48
#define MROWS (BB*LL)   // 2048
#define E2 (2*DI)       // 3072
#define EPSV 1e-5f
#define LOG2E 1.4426950408889634f
#define XPZ 12          // xp split-K factor (2 K-steps each)
#define OZ 2            // out-proj split-K factor
// scan geometry (R10-proven): 16 chunks x 16 d-lanes per block
#define CH2 16
#define LC2 (LL/CH2)    // 32

typedef __attribute__((ext_vector_type(8))) short bf16x8;
typedef __attribute__((ext_vector_type(4))) float f32x4;

#define GLL16(g, l) __builtin_amdgcn_global_load_lds( \
    (const __attribute__((address_space(1))) void*)(g), \
    (__attribute__((address_space(3))) void*)(l), 16, 0, 0)

__device__ inline float hw_exp2(float x) { return __builtin_amdgcn_exp2f(x); }

__device__ inline ushort f2bf(float f) {
  union { float f; unsigned u; } v; v.f = f;
  unsigned u = v.u;
  unsigned r = (u + 0x7fffu + ((u >> 16) & 1u)) >> 16;
  return (ushort)r;
}
__device__ inline float bf2f(ushort u) {
  union { unsigned u; float f; } v; v.u = ((unsigned)u) << 16; return v.f;
}

__device__ inline float block_sum(float v, volatile float* red) {
  #pragma unroll
  for (int o = 32; o > 0; o >>= 1) v += __shfl_down(v, o);
  if ((threadIdx.x & 63) == 0) red[threadIdx.x >> 6] = v;
  __syncthreads();
  float t = red[0] + red[1] + red[2] + red[3];
  __syncthreads();
  return t;
}

// ---------------- cvtA: in_W + out_W f32->bf16 ----------------
__global__ __launch_bounds__(256) void k_cvtA(const float* __restrict__ inW,
    const float* __restrict__ outW, ushort* __restrict__ wIn,
    ushort* __restrict__ wOut) {
  int i = blockIdx.x * 256 + threadIdx.x;
  const int nIn = NLAYER * E2 * DD / 4;
  const int nOut = NLAYER * DD * DI / 4;
  if (i < nIn) {
    float4 v = ((const float4*)inW)[i];
    ushort4 o = { f2bf(v.x), f2bf(v.y), f2bf(v.z), f2bf(v.w) };
    ((ushort4*)wIn)[i] = o;
  } else if (i < nIn + nOut) {
    int j = i - nIn;
    float4 v = ((const float4*)outW)[j];
    ushort4 o = { f2bf(v.x), f2bf(v.y), f2bf(v.z), f2bf(v.w) };
    ((ushort4*)wOut)[j] = o;
  }
}

// ---------------- cvtB: xp_W bf16; dt_W bf16 64-pad; conv_W transpose ----------------
__global__ __launch_bounds__(256) void k_cvtB(const float* __restrict__ xpW,
    const float* __restrict__ dtW, const float* __restrict__ convW,
    ushort* __restrict__ wXp, ushort* __restrict__ wDt, float* __restrict__ convWt) {
  int i = blockIdx.x * 256 + threadIdx.x;
  const int n0 = NLAYER * 80 * DI / 4;
  const int n1 = NLAYER * DI * 64;
  const int n2 = NLAYER * DI * 4;
  if (i < n0) {
    float4 v = ((const float4*)xpW)[i];
    ushort4 o = { f2bf(v.x), f2bf(v.y), f2bf(v.z), f2bf(v.w) };
    ((ushort4*)wXp)[i] = o;
  } else if (i < n0 + n1) {
    int j = i - n0;
    int r = j >> 6, c = j & 63;
    wDt[j] = (c < RR) ? f2bf(dtW[(size_t)r * RR + c]) : (ushort)0;
  } else if (i < n0 + n1 + n2) {
    int j = i - n0 - n1;
    int l = j / (DI * 4);
    int rem = j - l * (DI * 4);
    int d = rem >> 2, k = rem & 3;
    convWt[(size_t)l * 4 * DI + k * DI + d] = convW[(size_t)l * DI * 4 + d * 4 + k];
  }
}

// ---------------- embedding: resid = wte[ids] + wpe ----------------
__global__ __launch_bounds__(256) void k_embed(const int* __restrict__ ids,
    const float* __restrict__ wte, const float* __restrict__ wpe,
    float* __restrict__ resid) {
  const int nd4 = DD / 4;
  int i = blockIdx.x * 256 + threadIdx.x;
  if (i >= MROWS * nd4) return;
  int m = i / nd4, d4 = i - m * nd4;
  int l = m & (LL - 1);
  int tok = ids[m];
  float4 a = ((const float4*)wte)[(size_t)tok * nd4 + d4];
  float4 b = ((const float4*)wpe)[(size_t)l * nd4 + d4];
  float4 o; o.x = a.x + b.x; o.y = a.y + b.y; o.z = a.z + b.z; o.w = a.w + b.w;
  ((float4*)resid)[i] = o;
}

// ---------------- fused residual add (OZ bf16 partials) + layernorm -> bf16 ----------------
__global__ __launch_bounds__(256) void k_ln(const ushort* __restrict__ hidP,
    float* __restrict__ resid, const float* __restrict__ g, const float* __restrict__ b,
    ushort* __restrict__ hbf, int addHidden) {
  __shared__ float red[4];
  int m = blockIdx.x, t = threadIdx.x;
  size_t base = (size_t)m * DD;
  float x0 = resid[base + t], x1 = resid[base + t + 256], x2 = resid[base + t + 512];
  if (addHidden) {
    #pragma unroll
    for (int z = 0; z < OZ; ++z) {
      size_t bz = (size_t)z * MROWS * DD + base;
      x0 += bf2f(hidP[bz + t]); x1 += bf2f(hidP[bz + t + 256]); x2 += bf2f(hidP[bz + t + 512]);
    }
    resid[base + t] = x0; resid[base + t + 256] = x1; resid[base + t + 512] = x2;
  }
  float S  = block_sum(x0 + x1 + x2, red);
  float S2 = block_sum(x0*x0 + x1*x1 + x2*x2, red);
  float mu = S * (1.f / DD);
  float var = S2 * (1.f / DD) - mu * mu;
  float rs = rsqrtf(var + EPSV);
  hbf[base + t]       = f2bf((x0 - mu) * rs * g[t]       + b[t]);
  hbf[base + t + 256] = f2bf((x1 - mu) * rs * g[t + 256] + b[t + 256]);
  hbf[base + t + 512] = f2bf((x2 - mu) * rs * g[t + 512] + b[t + 512]);
}

// ---------------- 64x128 (MxN) MFMA GEMM, BK=64, NT, bf16 in ----------------
// OM=1: bf16 out. OM=2: bf16 softplus(acc + dtb[col]). OM=3: bf16 partials (z-offset).
template<int OM>
__global__ __launch_bounds__(256) void k_gemm64(const ushort* __restrict__ A,
    const ushort* __restrict__ Bw, void* __restrict__ Cv, const float* __restrict__ dtb,
    int N, int K, int kSteps) {
  __shared__ ushort lA[64 * 64];
  __shared__ ushort lB[128 * 64];
  int tid = threadIdx.x;
  int wid = tid >> 6, lane = tid & 63;
  int tm = blockIdx.y * 64, tn = blockIdx.x * 128;
  int kBase = blockIdx.z * kSteps * 64;
  int wr = (wid >> 1) * 32, wc = (wid & 1) * 64;
  int fr = lane & 15, kg = lane >> 4;
  int sR = lane >> 3;
  int sC = ((lane & 7) ^ sR) * 8;
  f32x4 acc[2][4];
  #pragma unroll
  for (int mi = 0; mi < 2; ++mi)
    #pragma unroll
    for (int ni = 0; ni < 4; ++ni)
      acc[mi][ni] = {0.f, 0.f, 0.f, 0.f};

  for (int ks = 0; ks < kSteps; ++ks) {
    int k0 = kBase + ks * 64;
    #pragma unroll
    for (int i = 0; i < 2; ++i) {
      int r0 = wid * 16 + i * 8;
      GLL16(A + (size_t)(tm + r0 + sR) * K + k0 + sC, &lA[r0 * 64]);
    }
    #pragma unroll
    for (int i = 0; i < 4; ++i) {
      int r0 = wid * 32 + i * 8;
      int brow = tn + r0 + sR;
      if (brow > N - 1) brow = N - 1;
      GLL16(Bw + (size_t)brow * K + k0 + sC, &lB[r0 * 64]);
    }
    __syncthreads();
    #pragma unroll
    for (int k2 = 0; k2 < 2; ++k2) {
      bf16x8 af[2], bfr[4];
      #pragma unroll
      for (int mi = 0; mi < 2; ++mi)
        af[mi] = *(const bf16x8*)&lA[(wr + mi * 16 + fr) * 64 + (((k2 * 4 + kg) ^ (fr & 7)) * 8)];
      #pragma unroll
      for (int ni = 0; ni < 4; ++ni)
        bfr[ni] = *(const bf16x8*)&lB[(wc + ni * 16 + fr) * 64 + (((k2 * 4 + kg) ^ (fr & 7)) * 8)];
      #pragma unroll
      for (int mi = 0; mi < 2; ++mi)
        #pragma unroll
        for (int ni = 0; ni < 4; ++ni)
          acc[mi][ni] = __builtin_amdgcn_mfma_f32_16x16x32_bf16(af[mi], bfr[ni], acc[mi][ni], 0, 0, 0);
    }
    __syncthreads();
  }
  int crow0 = tm + wr + kg * 4;
  int ccol0 = tn + wc + fr;
  if (OM == 1) {
    ushort* C = (ushort*)Cv;
    #pragma unroll
    for (int mi = 0; mi < 2; ++mi)
      #pragma unroll
      for (int ni = 0; ni < 4; ++ni) {
        int cc = ccol0 + ni * 16;
        if (cc < N) {
          #pragma unroll
          for (int j = 0; j < 4; ++j)
            C[(size_t)(crow0 + mi * 16 + j) * N + cc] = f2bf(acc[mi][ni][j]);
        }
      }
  } else if (OM == 2) {
    ushort* C = (ushort*)Cv;
    #pragma unroll
    for (int mi = 0; mi < 2; ++mi)
      #pragma unroll
      for (int ni = 0; ni < 4; ++ni) {
        int cc = ccol0 + ni * 16;
        if (cc < N) {
          float bv = dtb[cc];
          #pragma unroll
          for (int j = 0; j < 4; ++j) {
            float x = acc[mi][ni][j] + bv;
            float sp = (x > 20.f) ? x : log1pf(__expf(x));
            C[(size_t)(crow0 + mi * 16 + j) * N + cc] = f2bf(sp);
          }
        }
      }
  } else {
    ushort* C = (ushort*)Cv + (size_t)blockIdx.z * ((size_t)gridDim.y * 64) * N;
    #pragma unroll
    for (int mi = 0; mi < 2; ++mi)
      #pragma unroll
      for (int ni = 0; ni < 4; ++ni) {
        int cc = ccol0 + ni * 16;
        if (cc < N) {
          #pragma unroll
          for (int j = 0; j < 4; ++j)
            C[(size_t)(crow0 + mi * 16 + j) * N + cc] = f2bf(acc[mi][ni][j]);
        }
      }
  }
}

// ---------------- conv-fused xp GEMM (64-row, 2 K-steps/z): conv+silu in A-staging ----------------
// grid (1, MROWS/64, XPZ); z owns 128 channels. N=80: odd-wid waves keep only ni=0;
// wid3's B-staging (rows 96-127) feeds only discarded tiles -> skipped.
__global__ __launch_bounds__(256) void k_xpconv(const ushort* __restrict__ xz,
    const ushort* __restrict__ wXpL, const float* __restrict__ cwt,
    const float* __restrict__ cbl, ushort* __restrict__ xibf,
    float* __restrict__ xpPart) {
  __shared__ ushort lA[64 * 64];
  __shared__ ushort lB[128 * 64];
  int tid = threadIdx.x;
  int wid = tid >> 6, lane = tid & 63;
  int tm2 = blockIdx.y * 64;
  int kBase = blockIdx.z * 128;
  int wr = (wid >> 1) * 32, wc = (wid & 1) * 64;
  int fr = lane & 15, kg = lane >> 4;
  int sR = lane >> 3, sC = ((lane & 7) ^ sR) * 8;
  f32x4 acc[2][4];
  #pragma unroll
  for (int mi = 0; mi < 2; ++mi)
    #pragma unroll
    for (int ni = 0; ni < 4; ++ni)
      acc[mi][ni] = {0.f, 0.f, 0.f, 0.f};
  for (int ks = 0; ks < 2; ++ks) {
    int k0 = kBase + ks * 64;
    if (wid < 3) {
      #pragma unroll
      for (int i2 = 0; i2 < 4; ++i2) {
        int r0 = wid * 32 + i2 * 8;
        int brow = r0 + sR;
        if (brow > 79) brow = 79;
        GLL16(wXpL + (size_t)brow * DI + k0 + sC, &lB[r0 * 64]);
      }
    }
    #pragma unroll
    for (int c2 = 0; c2 < 2; ++c2) {
      int chunk = tid + c2 * 256;
      int row = chunk >> 3, cc8 = chunk & 7;
      int m = tm2 + row, l = m & (LL - 1);
      int gc = k0 + cc8 * 8;
      float a8[8];
      {
        float4 a = *(const float4*)&cbl[gc];
        float4 b = *(const float4*)&cbl[gc + 4];
        a8[0] = a.x; a8[1] = a.y; a8[2] = a.z; a8[3] = a.w;
        a8[4] = b.x; a8[5] = b.y; a8[6] = b.z; a8[7] = b.w;
      }
      #pragma unroll
      for (int t = 0; t < 4; ++t) {
        if (l - 3 + t >= 0) {
          float4 a = *(const float4*)&cwt[t * DI + gc];
          float4 b = *(const float4*)&cwt[t * DI + gc + 4];
          bf16x8 v = *(const bf16x8*)&xz[(size_t)(m - 3 + t) * E2 + gc];
          a8[0] += bf2f((ushort)v[0]) * a.x; a8[1] += bf2f((ushort)v[1]) * a.y;
          a8[2] += bf2f((ushort)v[2]) * a.z; a8[3] += bf2f((ushort)v[3]) * a.w;
          a8[4] += bf2f((ushort)v[4]) * b.x; a8[5] += bf2f((ushort)v[5]) * b.y;
          a8[6] += bf2f((ushort)v[6]) * b.z; a8[7] += bf2f((ushort)v[7]) * b.w;
        }
      }
      bf16x8 vo;
      #pragma unroll
      for (int j = 0; j < 8; ++j) {
        float sg = 1.f / (1.f + __expf(-a8[j]));
        vo[j] = (short)f2bf(a8[j] * sg);
      }
      *(bf16x8*)&lA[row * 64 + ((cc8 ^ (row & 7)) * 8)] = vo;
      *(bf16x8*)&xibf[(size_t)m * DI + gc] = vo;
    }
    __syncthreads();
    #pragma unroll
    for (int k2 = 0; k2 < 2; ++k2) {
      bf16x8 af[2], bf4[4];
      #pragma unroll
      for (int mi = 0; mi < 2; ++mi)
        af[mi] = *(const bf16x8*)&lA[(wr + mi * 16 + fr) * 64 + (((k2 * 4 + kg) ^ (fr & 7)) * 8)];
      #pragma unroll
      for (int ni = 0; ni < 4; ++ni) {
        if (wc + ni * 16 < 80) {
          bf4[ni] = *(const bf16x8*)&lB[(wc + ni * 16 + fr) * 64 + (((k2 * 4 + kg) ^ (fr & 7)) * 8)];
          #pragma unroll
          for (int mi = 0; mi < 2; ++mi)
            acc[mi][ni] = __builtin_amdgcn_mfma_f32_16x16x32_bf16(af[mi], bf4[ni], acc[mi][ni], 0, 0, 0);
        }
      }
    }
    __syncthreads();
  }
  int crow0 = tm2 + wr + kg * 4;
  int ccol0 = wc + fr;
  float* Cf = xpPart + (size_t)blockIdx.z * MROWS * 80;
  #pragma unroll
  for (int mi = 0; mi < 2; ++mi)
    #pragma unroll
    for (int ni = 0; ni < 4; ++ni) {
      int cc = ccol0 + ni * 16;
      if (cc < 80) {
        #pragma unroll
        for (int j = 0; j < 4; ++j)
          Cf[(size_t)(crow0 + mi * 16 + j) * 80 + cc] = acc[mi][ni][j];
      }
    }
}

// ---------------- combine xp split-K partials (XPZ) -> dblb f32 + dtbf bf16(padded) ----------------
__global__ __launch_bounds__(256) void k_comb_xp(const float* __restrict__ part,
    float* __restrict__ dblb, ushort* __restrict__ dtbf) {
  int i = blockIdx.x * 256 + threadIdx.x;
  if (i >= MROWS * 80) return;
  const int S = MROWS * 80;
  float s = 0.f;
  #pragma unroll
  for (int z = 0; z < XPZ; ++z) s += part[i + z * S];
  dblb[i] = s;
  int m = i / 80, c = i - m * 80;
  if (c < RR) dtbf[(size_t)m * 64 + c] = f2bf(s);
  else if (c < 64) dtbf[(size_t)m * 64 + c] = 0;
}

// ---------------- fused selective scan: 16 chunks x 16 d-lanes; grid (DI/16, BB) ----------------
__global__ __launch_bounds__(256) void k_scan_f(const ushort* __restrict__ delta,
    const ushort* __restrict__ ubf, const float* __restrict__ dblb,
    const ushort* __restrict__ xz, const float* __restrict__ A_log,
    const float* __restrict__ Dres, ushort* __restrict__ ybf, int layer) {
  __shared__ float shH[16 * 257];
  __shared__ float shP[16 * 257];
  int tid = threadIdx.x;
  int dloc = tid & 15, chunk = tid >> 4;
  int d = blockIdx.x * 16 + dloc;
  int b = blockIdx.y;
  float an[16];
  {
    const float4* a4 = (const float4*)(A_log + ((size_t)layer * DI + d) * NS);
    #pragma unroll
    for (int q = 0; q < 4; ++q) {
      float4 v = a4[q];
      an[4*q]   = -__expf(v.x) * LOG2E; an[4*q+1] = -__expf(v.y) * LOG2E;
      an[4*q+2] = -__expf(v.z) * LOG2E; an[4*q+3] = -__expf(v.w) * LOG2E;
    }
  }
  int l0 = chunk * LC2;
  size_t rowd0 = ((size_t)b * LL + l0) * DI + d;
  size_t rowb0 = ((size_t)b * LL + l0) * 80 + RR;

  // ---- phase A: local scan; sumD replaces per-n product chain ----
  float h[16];
  float sumD = 0.f;
  #pragma unroll
  for (int n = 0; n < 16; ++n) h[n] = 0.f;
  {
    size_t rd = rowd0, rb = rowb0;
    float dl = bf2f(delta[rd]);
    float uv = bf2f(ubf[rd]);
    float4 b0 = *(const float4*)(dblb + rb),     b1 = *(const float4*)(dblb + rb + 4);
    float4 b2 = *(const float4*)(dblb + rb + 8), b3 = *(const float4*)(dblb + rb + 12);
    for (int l = 0; l < LC2; ++l) {
      float dlc = dl, uvc = uv;
      float4 c0 = b0, c1 = b1, c2 = b2, c3 = b3;
      if (l + 1 < LC2) {
        rd += DI; rb += 80;
        dl = bf2f(delta[rd]); uv = bf2f(ubf[rd]);
        b0 = *(const float4*)(dblb + rb);     b1 = *(const float4*)(dblb + rb + 4);
        b2 = *(const float4*)(dblb + rb + 8); b3 = *(const float4*)(dblb + rb + 12);
      }
      float du = dlc * uvc;
      sumD += dlc;
      float Bv[16] = { c0.x, c0.y, c0.z, c0.w, c1.x, c1.y, c1.z, c1.w,
                       c2.x, c2.y, c2.z, c2.w, c3.x, c3.y, c3.z, c3.w };
      #pragma unroll
      for (int n = 0; n < 16; ++n) {
        float a = hw_exp2(dlc * an[n]);
        h[n] = h[n] * a + du * Bv[n];
      }
    }
  }
  {
    int base = dloc * 257 + chunk * 16;
    #pragma unroll
    for (int n = 0; n < 16; ++n) {
      shH[base + n] = h[n];
      shP[base + n] = hw_exp2(an[n] * sumD);
    }
  }
  __syncthreads();

  // ---- phase B: sequential combine across chunks (16 d x 16 n = 256 threads) ----
  {
    int n2 = tid & 15, dl2 = tid >> 4;
    float hh = 0.f;
    int base = dl2 * 257;
    for (int c = 0; c < CH2; ++c) {
      int idx = base + c * 16 + n2;
      float t = shH[idx], p = shP[idx];
      shH[idx] = hh;
      hh = t + p * hh;
    }
  }
  __syncthreads();

  // ---- phase C: rescan from corrected h_in, fused y + gate -> bf16 ----
  {
    int base = dloc * 257 + chunk * 16;
    #pragma unroll
    for (int n = 0; n < 16; ++n) h[n] = shH[base + n];
  }
  float dresv = Dres[(size_t)layer * DI + d];
  {
    size_t rd = rowd0, rb = rowb0;
    size_t rz = ((size_t)b * LL + l0) * E2 + DI + d;
    float dl = bf2f(delta[rd]);
    float uv = bf2f(ubf[rd]);
    float4 b0 = *(const float4*)(dblb + rb),      b1 = *(const float4*)(dblb + rb + 4);
    float4 b2 = *(const float4*)(dblb + rb + 8),  b3 = *(const float4*)(dblb + rb + 12);
    float4 e0 = *(const float4*)(dblb + rb + 16), e1 = *(const float4*)(dblb + rb + 20);
    float4 e2 = *(const float4*)(dblb + rb + 24), e3 = *(const float4*)(dblb + rb + 28);
    for (int l = 0; l < LC2; ++l) {
      float dlc = dl, uvc = uv;
      float4 c0 = b0, c1 = b1, c2 = b2, c3 = b3;
      float4 f0 = e0, f1 = e1, f2 = e2, f3 = e3;
      size_t rdc = rd, rzc = rz;
      if (l + 1 < LC2) {
        rd += DI; rb += 80; rz += E2;
        dl = bf2f(delta[rd]); uv = bf2f(ubf[rd]);
        b0 = *(const float4*)(dblb + rb);      b1 = *(const float4*)(dblb + rb + 4);
        b2 = *(const float4*)(dblb + rb + 8);  b3 = *(const float4*)(dblb + rb + 12);
        e0 = *(const float4*)(dblb + rb + 16); e1 = *(const float4*)(dblb + rb + 20);
        e2 = *(const float4*)(dblb + rb + 24); e3 = *(const float4*)(dblb + rb + 28);
      }
      float du = dlc * uvc;
      float Bv[16] = { c0.x, c0.y, c0.z, c0.w, c1.x, c1.y, c1.z, c1.w,
                       c2.x, c2.y, c2.z, c2.w, c3.x, c3.y, c3.z, c3.w };
      float Cv[16] = { f0.x, f0.y, f0.z, f0.w, f1.x, f1.y, f1.z, f1.w,
                       f2.x, f2.y, f2.z, f2.w, f3.x, f3.y, f3.z, f3.w };
      float y = 0.f;
      #pragma unroll
      for (int n = 0; n < 16; ++n) {
        float a = hw_exp2(dlc * an[n]);
        h[n] = h[n] * a + du * Bv[n];
        y += h[n] * Cv[n];
      }
      float zv = bf2f(xz[rzc]);
      float yt = y + uvc * dresv;
      float sg = 1.f / (1.f + __expf(-zv));
      ybf[rdc] = f2bf(yt * (zv * sg));
    }
  }
}

// ---------------- final: resid += sum(hidP bf16); out = LN(LN(resid,nf),fin) ----------------
__global__ __launch_bounds__(256) void k_final(const float* __restrict__ resid,
    const ushort* __restrict__ hidP,
    const float* __restrict__ nfg, const float* __restrict__ nfb,
    const float* __restrict__ fig, const float* __restrict__ fib,
    float* __restrict__ out) {
  __shared__ float red[4];
  int m = blockIdx.x, t = threadIdx.x;
  size_t base = (size_t)m * DD;
  float x0 = resid[base + t], x1 = resid[base + t + 256], x2 = resid[base + t + 512];
  #pragma unroll
  for (int z = 0; z < OZ; ++z) {
    size_t bz = (size_t)z * MROWS * DD + base;
    x0 += bf2f(hidP[bz + t]); x1 += bf2f(hidP[bz + t + 256]); x2 += bf2f(hidP[bz + t + 512]);
  }
  float S  = block_sum(x0 + x1 + x2, red);
  float S2 = block_sum(x0*x0 + x1*x1 + x2*x2, red);
  float mu = S * (1.f / DD);
  float var = S2 * (1.f / DD) - mu * mu;
  float rs = rsqrtf(var + EPSV);
  float t0 = (x0 - mu) * rs * nfg[t]       + nfb[t];
  float t1 = (x1 - mu) * rs * nfg[t + 256] + nfb[t + 256];
  float t2 = (x2 - mu) * rs * nfg[t + 512] + nfb[t + 512];
  S  = block_sum(t0 + t1 + t2, red);
  S2 = block_sum(t0*t0 + t1*t1 + t2*t2, red);
  mu = S * (1.f / DD);
  var = S2 * (1.f / DD) - mu * mu;
  rs = rsqrtf(var + EPSV);
  out[base + t]       = (t0 - mu) * rs * fig[t]       + fib[t];
  out[base + t + 256] = (t1 - mu) * rs * fig[t + 256] + fib[t + 256];
  out[base + t + 512] = (t2 - mu) * rs * fig[t + 512] + fib[t + 512];
}

extern "C" void kernel_launch(void* const* d_in, const int* in_sizes, int n_in,
                              void* d_out, int out_size, void* d_ws, size_t ws_size,
                              hipStream_t stream) {
  const int*   ids    = (const int*)  d_in[0];
  const float* wte    = (const float*)d_in[1];
  const float* wpe    = (const float*)d_in[2];
  const float* ln_g   = (const float*)d_in[3];
  const float* ln_b   = (const float*)d_in[4];
  const float* in_W   = (const float*)d_in[5];
  const float* conv_W = (const float*)d_in[6];
  const float* conv_b = (const float*)d_in[7];
  const float* xp_W   = (const float*)d_in[8];
  const float* dt_W   = (const float*)d_in[9];
  const float* dt_b   = (const float*)d_in[10];
  const float* A_log  = (const float*)d_in[11];
  const float* Dres   = (const float*)d_in[12];
  const float* out_W  = (const float*)d_in[13];
  const float* nf_g   = (const float*)d_in[14];
  const float* nf_b   = (const float*)d_in[15];
  const float* fin_g  = (const float*)d_in[16];
  const float* fin_b  = (const float*)d_in[17];

  char* p = (char*)d_ws;
  auto take = [&](size_t bytes) {
    char* r = p; p += (bytes + 255) & ~(size_t)255; return r;
  };
  float*  resid  = (float*) take((size_t)MROWS * DD * 4);
  ushort* hidP   = (ushort*)take((size_t)OZ * MROWS * DD * 2);
  ushort* h_bf   = (ushort*)take((size_t)MROWS * DD * 2);
  ushort* xz     = (ushort*)take((size_t)MROWS * E2 * 2);
  ushort* xibf   = (ushort*)take((size_t)MROWS * DI * 2);
  float*  xpPart = (float*) take((size_t)XPZ * MROWS * 80 * 4);
  float*  dblb   = (float*) take((size_t)MROWS * 80 * 4);
  ushort* dtbf   = (ushort*)take((size_t)MROWS * 64 * 2);
  ushort* delta  = (ushort*)take((size_t)MROWS * DI * 2);
  ushort* ybf    = (ushort*)take((size_t)MROWS * DI * 2);
  ushort* wInBf  = (ushort*)take((size_t)NLAYER * E2 * DD * 2);
  ushort* wXpBf  = (ushort*)take((size_t)NLAYER * 80 * DI * 2);
  ushort* wDtBf  = (ushort*)take((size_t)NLAYER * DI * 64 * 2);
  ushort* wOutBf = (ushort*)take((size_t)NLAYER * DD * DI * 2);
  float*  convWt = (float*) take((size_t)NLAYER * 4 * DI * 4);

  {
    int total = NLAYER * E2 * DD / 4 + NLAYER * DD * DI / 4;
    k_cvtA<<<(total + 255) / 256, 256, 0, stream>>>(in_W, out_W, wInBf, wOutBf);
  }
  {
    int total = NLAYER * 80 * DI / 4 + NLAYER * DI * 64 + NLAYER * DI * 4;
    k_cvtB<<<(total + 255) / 256, 256, 0, stream>>>(xp_W, dt_W, conv_W,
                                                    wXpBf, wDtBf, convWt);
  }
  k_embed<<<(MROWS * (DD / 4) + 255) / 256, 256, 0, stream>>>(ids, wte, wpe, resid);

  for (int i = 0; i < NLAYER; ++i) {
    k_ln<<<MROWS, 256, 0, stream>>>(hidP, resid,
                                    ln_g + (size_t)i * DD, ln_b + (size_t)i * DD,
                                    h_bf, i > 0 ? 1 : 0);

    { dim3 g(E2 / 128, MROWS / 64, 1);    // 24 x 32 = 768 blocks
      k_gemm64<1><<<g, 256, 0, stream>>>(h_bf, wInBf + (size_t)i * E2 * DD,
                                         (void*)xz, nullptr, E2, DD, DD / 64); }

    { dim3 g(1, MROWS / 64, XPZ);         // 32 x 12 = 384 blocks, 2 K-steps
      k_xpconv<<<g, 256, 0, stream>>>(xz, wXpBf + (size_t)i * 80 * DI,
                                      convWt + (size_t)i * 4 * DI,
                                      conv_b + (size_t)i * DI, xibf, xpPart); }

    k_comb_xp<<<(MROWS * 80 + 255) / 256, 256, 0, stream>>>(xpPart, dblb, dtbf);

    { dim3 g(DI / 128, MROWS / 64, 1);    // 12 x 32 = 384 blocks, K=64
      k_gemm64<2><<<g, 256, 0, stream>>>(dtbf, wDtBf + (size_t)i * DI * 64,
                                         (void*)delta, dt_b + (size_t)i * DI, DI, 64, 1); }

    { dim3 g(DI / 16, BB);                // 96 x 4 = 384 blocks
      k_scan_f<<<g, 256, 0, stream>>>(delta, xibf, dblb, xz, A_log, Dres, ybf, i); }

    { dim3 g(DD / 128, MROWS / 64, OZ);   // 6 x 32 x 2 = 384 blocks, 12 stages
      k_gemm64<3><<<g, 256, 0, stream>>>(ybf, wOutBf + (size_t)i * DD * DI,
                                         (void*)hidP, nullptr, DD, DI, DI / 64 / OZ); }
  }

  k_final<<<MROWS, 256, 0, stream>>>(resid, hidP, nf_g, nf_b,
                                     fin_g, fin_b, (float*)d_out);
}

// Round 15
// 1340.758 us; speedup vs baseline: 1.0638x; 1.0004x over previous
//
#include <hip/hip_runtime.h>

#define BB 4
#define LL 512
#define DD 768
#define NLAYER 12
#define DI 1536
#define NS 16
#define KC 4
#define RR 48
#define MROWS (BB*LL)   // 2048
#define E2 (2*DI)       // 3072
#define EPSV 1e-5f
#define LOG2E 1.4426950408889634f
#define XPZ 12          // xp split-K factor (2 K-steps each)
#define OZ 2            // out-proj split-K factor
#define CH2 16
#define LC2 (LL/CH2)    // 32

typedef __attribute__((ext_vector_type(8))) short bf16x8;
typedef __attribute__((ext_vector_type(4))) float f32x4;

#define GLL16(g, l) __builtin_amdgcn_global_load_lds( \
    (const __attribute__((address_space(1))) void*)(g), \
    (__attribute__((address_space(3))) void*)(l), 16, 0, 0)

__device__ inline float hw_exp2(float x) { return __builtin_amdgcn_exp2f(x); }

__device__ inline ushort f2bf(float f) {
  union { float f; unsigned u; } v; v.f = f;
  unsigned u = v.u;
  unsigned r = (u + 0x7fffu + ((u >> 16) & 1u)) >> 16;
  return (ushort)r;
}
__device__ inline float bf2f(ushort u) {
  union { unsigned u; float f; } v; v.u = ((unsigned)u) << 16; return v.f;
}

// XCD-aware bijective block remap (requires nwg % 8 == 0), by-fastest decode.
__device__ inline void xcd_swz(int& bx, int& by, int& bz) {
  int gx = gridDim.x, gy = gridDim.y;
  int nwg = gx * gy * gridDim.z;
  int flat = (blockIdx.z * gy + blockIdx.y) * gx + blockIdx.x;
  int cpx = nwg >> 3;
  int swz = (flat & 7) * cpx + (flat >> 3);
  by = swz % gy;
  int t2 = swz / gy;
  bx = t2 % gx;
  bz = t2 / gx;
}

// fused 2-value block reduction: one shuffle tree + one barrier pair
__device__ inline void block_sum2(float a, float b, volatile float* red,
                                  float& oa, float& ob) {
  #pragma unroll
  for (int o = 32; o > 0; o >>= 1) {
    a += __shfl_down(a, o);
    b += __shfl_down(b, o);
  }
  int w = threadIdx.x >> 6;
  if ((threadIdx.x & 63) == 0) { red[w] = a; red[4 + w] = b; }
  __syncthreads();
  oa = red[0] + red[1] + red[2] + red[3];
  ob = red[4] + red[5] + red[6] + red[7];
  __syncthreads();
}

// ---------------- cvtA: in_W + out_W f32->bf16 ----------------
__global__ __launch_bounds__(256) void k_cvtA(const float* __restrict__ inW,
    const float* __restrict__ outW, ushort* __restrict__ wIn,
    ushort* __restrict__ wOut) {
  int i = blockIdx.x * 256 + threadIdx.x;
  const int nIn = NLAYER * E2 * DD / 4;
  const int nOut = NLAYER * DD * DI / 4;
  if (i < nIn) {
    float4 v = ((const float4*)inW)[i];
    ushort4 o = { f2bf(v.x), f2bf(v.y), f2bf(v.z), f2bf(v.w) };
    ((ushort4*)wIn)[i] = o;
  } else if (i < nIn + nOut) {
    int j = i - nIn;
    float4 v = ((const float4*)outW)[j];
    ushort4 o = { f2bf(v.x), f2bf(v.y), f2bf(v.z), f2bf(v.w) };
    ((ushort4*)wOut)[j] = o;
  }
}

// ---------------- cvtB: xp_W bf16; dt_W bf16 64-pad; conv_W transpose ----------------
__global__ __launch_bounds__(256) void k_cvtB(const float* __restrict__ xpW,
    const float* __restrict__ dtW, const float* __restrict__ convW,
    ushort* __restrict__ wXp, ushort* __restrict__ wDt, float* __restrict__ convWt) {
  int i = blockIdx.x * 256 + threadIdx.x;
  const int n0 = NLAYER * 80 * DI / 4;
  const int n1 = NLAYER * DI * 64;
  const int n2 = NLAYER * DI * 4;
  if (i < n0) {
    float4 v = ((const float4*)xpW)[i];
    ushort4 o = { f2bf(v.x), f2bf(v.y), f2bf(v.z), f2bf(v.w) };
    ((ushort4*)wXp)[i] = o;
  } else if (i < n0 + n1) {
    int j = i - n0;
    int r = j >> 6, c = j & 63;
    wDt[j] = (c < RR) ? f2bf(dtW[(size_t)r * RR + c]) : (ushort)0;
  } else if (i < n0 + n1 + n2) {
    int j = i - n0 - n1;
    int l = j / (DI * 4);
    int rem = j - l * (DI * 4);
    int d = rem >> 2, k = rem & 3;
    convWt[(size_t)l * 4 * DI + k * DI + d] = convW[(size_t)l * DI * 4 + d * 4 + k];
  }
}

// ---------------- embedding: resid = wte[ids] + wpe ----------------
__global__ __launch_bounds__(256) void k_embed(const int* __restrict__ ids,
    const float* __restrict__ wte, const float* __restrict__ wpe,
    float* __restrict__ resid) {
  const int nd4 = DD / 4;
  int i = blockIdx.x * 256 + threadIdx.x;
  if (i >= MROWS * nd4) return;
  int m = i / nd4, d4 = i - m * nd4;
  int l = m & (LL - 1);
  int tok = ids[m];
  float4 a = ((const float4*)wte)[(size_t)tok * nd4 + d4];
  float4 b = ((const float4*)wpe)[(size_t)l * nd4 + d4];
  float4 o; o.x = a.x + b.x; o.y = a.y + b.y; o.z = a.z + b.z; o.w = a.w + b.w;
  ((float4*)resid)[i] = o;
}

// ---------------- fused residual add (OZ bf16 partials) + layernorm -> bf16 ----------------
__global__ __launch_bounds__(256) void k_ln(const ushort* __restrict__ hidP,
    float* __restrict__ resid, const float* __restrict__ g, const float* __restrict__ b,
    ushort* __restrict__ hbf, int addHidden) {
  __shared__ float red[8];
  int m = blockIdx.x, t = threadIdx.x;
  size_t base = (size_t)m * DD;
  float x0 = resid[base + t], x1 = resid[base + t + 256], x2 = resid[base + t + 512];
  if (addHidden) {
    #pragma unroll
    for (int z = 0; z < OZ; ++z) {
      size_t bz = (size_t)z * MROWS * DD + base;
      x0 += bf2f(hidP[bz + t]); x1 += bf2f(hidP[bz + t + 256]); x2 += bf2f(hidP[bz + t + 512]);
    }
    resid[base + t] = x0; resid[base + t + 256] = x1; resid[base + t + 512] = x2;
  }
  float S, S2;
  block_sum2(x0 + x1 + x2, x0*x0 + x1*x1 + x2*x2, red, S, S2);
  float mu = S * (1.f / DD);
  float var = S2 * (1.f / DD) - mu * mu;
  float rs = rsqrtf(var + EPSV);
  hbf[base + t]       = f2bf((x0 - mu) * rs * g[t]       + b[t]);
  hbf[base + t + 256] = f2bf((x1 - mu) * rs * g[t + 256] + b[t + 256]);
  hbf[base + t + 512] = f2bf((x2 - mu) * rs * g[t + 512] + b[t + 512]);
}

// ---------------- 64x128 (MxN) MFMA GEMM, BK=64, NT, bf16 in, XCD-swizzled ----------------
// OM=1: bf16 out. OM=2: bf16 softplus(acc + dtb[col]). OM=3: bf16 partials (z-offset).
template<int OM>
__global__ __launch_bounds__(256) void k_gemm64(const ushort* __restrict__ A,
    const ushort* __restrict__ Bw, void* __restrict__ Cv, const float* __restrict__ dtb,
    int N, int K, int kSteps) {
  __shared__ ushort lA[64 * 64];
  __shared__ ushort lB[128 * 64];
  int bx, by, bz;
  xcd_swz(bx, by, bz);
  int tid = threadIdx.x;
  int wid = tid >> 6, lane = tid & 63;
  int tm = by * 64, tn = bx * 128;
  int kBase = bz * kSteps * 64;
  int wr = (wid >> 1) * 32, wc = (wid & 1) * 64;
  int fr = lane & 15, kg = lane >> 4;
  int sR = lane >> 3;
  int sC = ((lane & 7) ^ sR) * 8;
  f32x4 acc[2][4];
  #pragma unroll
  for (int mi = 0; mi < 2; ++mi)
    #pragma unroll
    for (int ni = 0; ni < 4; ++ni)
      acc[mi][ni] = {0.f, 0.f, 0.f, 0.f};

  for (int ks = 0; ks < kSteps; ++ks) {
    int k0 = kBase + ks * 64;
    #pragma unroll
    for (int i = 0; i < 2; ++i) {
      int r0 = wid * 16 + i * 8;
      GLL16(A + (size_t)(tm + r0 + sR) * K + k0 + sC, &lA[r0 * 64]);
    }
    #pragma unroll
    for (int i = 0; i < 4; ++i) {
      int r0 = wid * 32 + i * 8;
      int brow = tn + r0 + sR;
      if (brow > N - 1) brow = N - 1;
      GLL16(Bw + (size_t)brow * K + k0 + sC, &lB[r0 * 64]);
    }
    __syncthreads();
    #pragma unroll
    for (int k2 = 0; k2 < 2; ++k2) {
      bf16x8 af[2], bfr[4];
      #pragma unroll
      for (int mi = 0; mi < 2; ++mi)
        af[mi] = *(const bf16x8*)&lA[(wr + mi * 16 + fr) * 64 + (((k2 * 4 + kg) ^ (fr & 7)) * 8)];
      #pragma unroll
      for (int ni = 0; ni < 4; ++ni)
        bfr[ni] = *(const bf16x8*)&lB[(wc + ni * 16 + fr) * 64 + (((k2 * 4 + kg) ^ (fr & 7)) * 8)];
      #pragma unroll
      for (int mi = 0; mi < 2; ++mi)
        #pragma unroll
        for (int ni = 0; ni < 4; ++ni)
          acc[mi][ni] = __builtin_amdgcn_mfma_f32_16x16x32_bf16(af[mi], bfr[ni], acc[mi][ni], 0, 0, 0);
    }
    __syncthreads();
  }
  int crow0 = tm + wr + kg * 4;
  int ccol0 = tn + wc + fr;
  if (OM == 1) {
    ushort* C = (ushort*)Cv;
    #pragma unroll
    for (int mi = 0; mi < 2; ++mi)
      #pragma unroll
      for (int ni = 0; ni < 4; ++ni) {
        int cc = ccol0 + ni * 16;
        if (cc < N) {
          #pragma unroll
          for (int j = 0; j < 4; ++j)
            C[(size_t)(crow0 + mi * 16 + j) * N + cc] = f2bf(acc[mi][ni][j]);
        }
      }
  } else if (OM == 2) {
    ushort* C = (ushort*)Cv;
    #pragma unroll
    for (int mi = 0; mi < 2; ++mi)
      #pragma unroll
      for (int ni = 0; ni < 4; ++ni) {
        int cc = ccol0 + ni * 16;
        if (cc < N) {
          float bv = dtb[cc];
          #pragma unroll
          for (int j = 0; j < 4; ++j) {
            float x = acc[mi][ni][j] + bv;
            float sp = (x > 20.f) ? x : log1pf(__expf(x));
            C[(size_t)(crow0 + mi * 16 + j) * N + cc] = f2bf(sp);
          }
        }
      }
  } else {
    ushort* C = (ushort*)Cv + (size_t)bz * ((size_t)gridDim.y * 64) * N;
    #pragma unroll
    for (int mi = 0; mi < 2; ++mi)
      #pragma unroll
      for (int ni = 0; ni < 4; ++ni) {
        int cc = ccol0 + ni * 16;
        if (cc < N) {
          #pragma unroll
          for (int j = 0; j < 4; ++j)
            C[(size_t)(crow0 + mi * 16 + j) * N + cc] = f2bf(acc[mi][ni][j]);
        }
      }
  }
}

// ---------------- conv-fused xp GEMM (64-row, 2 K-steps/z): conv+silu in A-staging ----------------
__global__ __launch_bounds__(256) void k_xpconv(const ushort* __restrict__ xz,
    const ushort* __restrict__ wXpL, const float* __restrict__ cwt,
    const float* __restrict__ cbl, ushort* __restrict__ xibf,
    float* __restrict__ xpPart) {
  __shared__ ushort lA[64 * 64];
  __shared__ ushort lB[128 * 64];
  int bx, by, bz;
  xcd_swz(bx, by, bz);
  (void)bx;
  int tid = threadIdx.x;
  int wid = tid >> 6, lane = tid & 63;
  int tm2 = by * 64;
  int kBase = bz * 128;
  int wr = (wid >> 1) * 32, wc = (wid & 1) * 64;
  int fr = lane & 15, kg = lane >> 4;
  int sR = lane >> 3, sC = ((lane & 7) ^ sR) * 8;
  f32x4 acc[2][4];
  #pragma unroll
  for (int mi = 0; mi < 2; ++mi)
    #pragma unroll
    for (int ni = 0; ni < 4; ++ni)
      acc[mi][ni] = {0.f, 0.f, 0.f, 0.f};
  for (int ks = 0; ks < 2; ++ks) {
    int k0 = kBase + ks * 64;
    if (wid < 3) {
      #pragma unroll
      for (int i2 = 0; i2 < 4; ++i2) {
        int r0 = wid * 32 + i2 * 8;
        int brow = r0 + sR;
        if (brow > 79) brow = 79;
        GLL16(wXpL + (size_t)brow * DI + k0 + sC, &lB[r0 * 64]);
      }
    }
    #pragma unroll
    for (int c2 = 0; c2 < 2; ++c2) {
      int chunk = tid + c2 * 256;
      int row = chunk >> 3, cc8 = chunk & 7;
      int m = tm2 + row, l = m & (LL - 1);
      int gc = k0 + cc8 * 8;
      float a8[8];
      {
        float4 a = *(const float4*)&cbl[gc];
        float4 b = *(const float4*)&cbl[gc + 4];
        a8[0] = a.x; a8[1] = a.y; a8[2] = a.z; a8[3] = a.w;
        a8[4] = b.x; a8[5] = b.y; a8[6] = b.z; a8[7] = b.w;
      }
      #pragma unroll
      for (int t = 0; t < 4; ++t) {
        if (l - 3 + t >= 0) {
          float4 a = *(const float4*)&cwt[t * DI + gc];
          float4 b = *(const float4*)&cwt[t * DI + gc + 4];
          bf16x8 v = *(const bf16x8*)&xz[(size_t)(m - 3 + t) * E2 + gc];
          a8[0] += bf2f((ushort)v[0]) * a.x; a8[1] += bf2f((ushort)v[1]) * a.y;
          a8[2] += bf2f((ushort)v[2]) * a.z; a8[3] += bf2f((ushort)v[3]) * a.w;
          a8[4] += bf2f((ushort)v[4]) * b.x; a8[5] += bf2f((ushort)v[5]) * b.y;
          a8[6] += bf2f((ushort)v[6]) * b.z; a8[7] += bf2f((ushort)v[7]) * b.w;
        }
      }
      bf16x8 vo;
      #pragma unroll
      for (int j = 0; j < 8; ++j) {
        float sg = 1.f / (1.f + __expf(-a8[j]));
        vo[j] = (short)f2bf(a8[j] * sg);
      }
      *(bf16x8*)&lA[row * 64 + ((cc8 ^ (row & 7)) * 8)] = vo;
      *(bf16x8*)&xibf[(size_t)m * DI + gc] = vo;
    }
    __syncthreads();
    #pragma unroll
    for (int k2 = 0; k2 < 2; ++k2) {
      bf16x8 af[2], bf4[4];
      #pragma unroll
      for (int mi = 0; mi < 2; ++mi)
        af[mi] = *(const bf16x8*)&lA[(wr + mi * 16 + fr) * 64 + (((k2 * 4 + kg) ^ (fr & 7)) * 8)];
      #pragma unroll
      for (int ni = 0; ni < 4; ++ni) {
        if (wc + ni * 16 < 80) {
          bf4[ni] = *(const bf16x8*)&lB[(wc + ni * 16 + fr) * 64 + (((k2 * 4 + kg) ^ (fr & 7)) * 8)];
          #pragma unroll
          for (int mi = 0; mi < 2; ++mi)
            acc[mi][ni] = __builtin_amdgcn_mfma_f32_16x16x32_bf16(af[mi], bf4[ni], acc[mi][ni], 0, 0, 0);
        }
      }
    }
    __syncthreads();
  }
  int crow0 = tm2 + wr + kg * 4;
  int ccol0 = wc + fr;
  float* Cf = xpPart + (size_t)bz * MROWS * 80;
  #pragma unroll
  for (int mi = 0; mi < 2; ++mi)
    #pragma unroll
    for (int ni = 0; ni < 4; ++ni) {
      int cc = ccol0 + ni * 16;
      if (cc < 80) {
        #pragma unroll
        for (int j = 0; j < 4; ++j)
          Cf[(size_t)(crow0 + mi * 16 + j) * 80 + cc] = acc[mi][ni][j];
      }
    }
}

// ---------------- combine xp split-K partials (XPZ) -> dblb f32 + dtbf bf16(padded) ----------------
__global__ __launch_bounds__(256) void k_comb_xp(const float* __restrict__ part,
    float* __restrict__ dblb, ushort* __restrict__ dtbf) {
  int i = blockIdx.x * 256 + threadIdx.x;
  if (i >= MROWS * 80) return;
  const int S = MROWS * 80;
  float s = 0.f;
  #pragma unroll
  for (int z = 0; z < XPZ; ++z) s += part[i + z * S];
  dblb[i] = s;
  int m = i / 80, c = i - m * 80;
  if (c < RR) dtbf[(size_t)m * 64 + c] = f2bf(s);
  else if (c < 64) dtbf[(size_t)m * 64 + c] = 0;
}

// ---------------- fused selective scan: 16 chunks x 16 d-lanes; grid (DI/16, BB) ----------------
__global__ __launch_bounds__(256) void k_scan_f(const ushort* __restrict__ delta,
    const ushort* __restrict__ ubf, const float* __restrict__ dblb,
    const ushort* __restrict__ xz, const float* __restrict__ A_log,
    const float* __restrict__ Dres, ushort* __restrict__ ybf, int layer) {
  __shared__ float shH[16 * 257];
  __shared__ float shP[16 * 257];
  int tid = threadIdx.x;
  int dloc = tid & 15, chunk = tid >> 4;
  int d = blockIdx.x * 16 + dloc;
  int b = blockIdx.y;
  float an[16];
  {
    const float4* a4 = (const float4*)(A_log + ((size_t)layer * DI + d) * NS);
    #pragma unroll
    for (int q = 0; q < 4; ++q) {
      float4 v = a4[q];
      an[4*q]   = -__expf(v.x) * LOG2E; an[4*q+1] = -__expf(v.y) * LOG2E;
      an[4*q+2] = -__expf(v.z) * LOG2E; an[4*q+3] = -__expf(v.w) * LOG2E;
    }
  }
  int l0 = chunk * LC2;
  size_t rowd0 = ((size_t)b * LL + l0) * DI + d;
  size_t rowb0 = ((size_t)b * LL + l0) * 80 + RR;

  // ---- phase A: local scan; sumD replaces per-n product chain ----
  float h[16];
  float sumD = 0.f;
  #pragma unroll
  for (int n = 0; n < 16; ++n) h[n] = 0.f;
  {
    size_t rd = rowd0, rb = rowb0;
    float dl = bf2f(delta[rd]);
    float uv = bf2f(ubf[rd]);
    float4 b0 = *(const float4*)(dblb + rb),     b1 = *(const float4*)(dblb + rb + 4);
    float4 b2 = *(const float4*)(dblb + rb + 8), b3 = *(const float4*)(dblb + rb + 12);
    for (int l = 0; l < LC2; ++l) {
      float dlc = dl, uvc = uv;
      float4 c0 = b0, c1 = b1, c2 = b2, c3 = b3;
      if (l + 1 < LC2) {
        rd += DI; rb += 80;
        dl = bf2f(delta[rd]); uv = bf2f(ubf[rd]);
        b0 = *(const float4*)(dblb + rb);     b1 = *(const float4*)(dblb + rb + 4);
        b2 = *(const float4*)(dblb + rb + 8); b3 = *(const float4*)(dblb + rb + 12);
      }
      float du = dlc * uvc;
      sumD += dlc;
      float Bv[16] = { c0.x, c0.y, c0.z, c0.w, c1.x, c1.y, c1.z, c1.w,
                       c2.x, c2.y, c2.z, c2.w, c3.x, c3.y, c3.z, c3.w };
      #pragma unroll
      for (int n = 0; n < 16; ++n) {
        float a = hw_exp2(dlc * an[n]);
        h[n] = h[n] * a + du * Bv[n];
      }
    }
  }
  {
    int base = dloc * 257 + chunk * 16;
    #pragma unroll
    for (int n = 0; n < 16; ++n) {
      shH[base + n] = h[n];
      shP[base + n] = hw_exp2(an[n] * sumD);
    }
  }
  __syncthreads();

  // ---- phase B: sequential combine across chunks (16 d x 16 n = 256 threads) ----
  {
    int n2 = tid & 15, dl2 = tid >> 4;
    float hh = 0.f;
    int base = dl2 * 257;
    for (int c = 0; c < CH2; ++c) {
      int idx = base + c * 16 + n2;
      float t = shH[idx], p = shP[idx];
      shH[idx] = hh;
      hh = t + p * hh;
    }
  }
  __syncthreads();

  // ---- phase C: rescan from corrected h_in, fused y + gate -> bf16 ----
  {
    int base = dloc * 257 + chunk * 16;
    #pragma unroll
    for (int n = 0; n < 16; ++n) h[n] = shH[base + n];
  }
  float dresv = Dres[(size_t)layer * DI + d];
  {
    size_t rd = rowd0, rb = rowb0;
    size_t rz = ((size_t)b * LL + l0) * E2 + DI + d;
    float dl = bf2f(delta[rd]);
    float uv = bf2f(ubf[rd]);
    float4 b0 = *(const float4*)(dblb + rb),      b1 = *(const float4*)(dblb + rb + 4);
    float4 b2 = *(const float4*)(dblb + rb + 8),  b3 = *(const float4*)(dblb + rb + 12);
    float4 e0 = *(const float4*)(dblb + rb + 16), e1 = *(const float4*)(dblb + rb + 20);
    float4 e2 = *(const float4*)(dblb + rb + 24), e3 = *(const float4*)(dblb + rb + 28);
    for (int l = 0; l < LC2; ++l) {
      float dlc = dl, uvc = uv;
      float4 c0 = b0, c1 = b1, c2 = b2, c3 = b3;
      float4 f0 = e0, f1 = e1, f2 = e2, f3 = e3;
      size_t rdc = rd, rzc = rz;
      if (l + 1 < LC2) {
        rd += DI; rb += 80; rz += E2;
        dl = bf2f(delta[rd]); uv = bf2f(ubf[rd]);
        b0 = *(const float4*)(dblb + rb);      b1 = *(const float4*)(dblb + rb + 4);
        b2 = *(const float4*)(dblb + rb + 8);  b3 = *(const float4*)(dblb + rb + 12);
        e0 = *(const float4*)(dblb + rb + 16); e1 = *(const float4*)(dblb + rb + 20);
        e2 = *(const float4*)(dblb + rb + 24); e3 = *(const float4*)(dblb + rb + 28);
      }
      float du = dlc * uvc;
      float Bv[16] = { c0.x, c0.y, c0.z, c0.w, c1.x, c1.y, c1.z, c1.w,
                       c2.x, c2.y, c2.z, c2.w, c3.x, c3.y, c3.z, c3.w };
      float Cv[16] = { f0.x, f0.y, f0.z, f0.w, f1.x, f1.y, f1.z, f1.w,
                       f2.x, f2.y, f2.z, f2.w, f3.x, f3.y, f3.z, f3.w };
      float y = 0.f;
      #pragma unroll
      for (int n = 0; n < 16; ++n) {
        float a = hw_exp2(dlc * an[n]);
        h[n] = h[n] * a + du * Bv[n];
        y += h[n] * Cv[n];
      }
      float zv = bf2f(xz[rzc]);
      float yt = y + uvc * dresv;
      float sg = 1.f / (1.f + __expf(-zv));
      ybf[rdc] = f2bf(yt * (zv * sg));
    }
  }
}

// ---------------- final: resid += sum(hidP bf16); out = LN(LN(resid,nf),fin) ----------------
__global__ __launch_bounds__(256) void k_final(const float* __restrict__ resid,
    const ushort* __restrict__ hidP,
    const float* __restrict__ nfg, const float* __restrict__ nfb,
    const float* __restrict__ fig, const float* __restrict__ fib,
    float* __restrict__ out) {
  __shared__ float red[8];
  int m = blockIdx.x, t = threadIdx.x;
  size_t base = (size_t)m * DD;
  float x0 = resid[base + t], x1 = resid[base + t + 256], x2 = resid[base + t + 512];
  #pragma unroll
  for (int z = 0; z < OZ; ++z) {
    size_t bz = (size_t)z * MROWS * DD + base;
    x0 += bf2f(hidP[bz + t]); x1 += bf2f(hidP[bz + t + 256]); x2 += bf2f(hidP[bz + t + 512]);
  }
  float S, S2;
  block_sum2(x0 + x1 + x2, x0*x0 + x1*x1 + x2*x2, red, S, S2);
  float mu = S * (1.f / DD);
  float var = S2 * (1.f / DD) - mu * mu;
  float rs = rsqrtf(var + EPSV);
  float t0 = (x0 - mu) * rs * nfg[t]       + nfb[t];
  float t1 = (x1 - mu) * rs * nfg[t + 256] + nfb[t + 256];
  float t2 = (x2 - mu) * rs * nfg[t + 512] + nfb[t + 512];
  block_sum2(t0 + t1 + t2, t0*t0 + t1*t1 + t2*t2, red, S, S2);
  mu = S * (1.f / DD);
  var = S2 * (1.f / DD) - mu * mu;
  rs = rsqrtf(var + EPSV);
  out[base + t]       = (t0 - mu) * rs * fig[t]       + fib[t];
  out[base + t + 256] = (t1 - mu) * rs * fig[t + 256] + fib[t + 256];
  out[base + t + 512] = (t2 - mu) * rs * fig[t + 512] + fib[t + 512];
}

extern "C" void kernel_launch(void* const* d_in, const int* in_sizes, int n_in,
                              void* d_out, int out_size, void* d_ws, size_t ws_size,
                              hipStream_t stream) {
  const int*   ids    = (const int*)  d_in[0];
  const float* wte    = (const float*)d_in[1];
  const float* wpe    = (const float*)d_in[2];
  const float* ln_g   = (const float*)d_in[3];
  const float* ln_b   = (const float*)d_in[4];
  const float* in_W   = (const float*)d_in[5];
  const float* conv_W = (const float*)d_in[6];
  const float* conv_b = (const float*)d_in[7];
  const float* xp_W   = (const float*)d_in[8];
  const float* dt_W   = (const float*)d_in[9];
  const float* dt_b   = (const float*)d_in[10];
  const float* A_log  = (const float*)d_in[11];
  const float* Dres   = (const float*)d_in[12];
  const float* out_W  = (const float*)d_in[13];
  const float* nf_g   = (const float*)d_in[14];
  const float* nf_b   = (const float*)d_in[15];
  const float* fin_g  = (const float*)d_in[16];
  const float* fin_b  = (const float*)d_in[17];

  char* p = (char*)d_ws;
  auto take = [&](size_t bytes) {
    char* r = p; p += (bytes + 255) & ~(size_t)255; return r;
  };
  float*  resid  = (float*) take((size_t)MROWS * DD * 4);
  ushort* hidP   = (ushort*)take((size_t)OZ * MROWS * DD * 2);
  ushort* h_bf   = (ushort*)take((size_t)MROWS * DD * 2);
  ushort* xz     = (ushort*)take((size_t)MROWS * E2 * 2);
  ushort* xibf   = (ushort*)take((size_t)MROWS * DI * 2);
  float*  xpPart = (float*) take((size_t)XPZ * MROWS * 80 * 4);
  float*  dblb   = (float*) take((size_t)MROWS * 80 * 4);
  ushort* dtbf   = (ushort*)take((size_t)MROWS * 64 * 2);
  ushort* delta  = (ushort*)take((size_t)MROWS * DI * 2);
  ushort* ybf    = (ushort*)take((size_t)MROWS * DI * 2);
  ushort* wInBf  = (ushort*)take((size_t)NLAYER * E2 * DD * 2);
  ushort* wXpBf  = (ushort*)take((size_t)NLAYER * 80 * DI * 2);
  ushort* wDtBf  = (ushort*)take((size_t)NLAYER * DI * 64 * 2);
  ushort* wOutBf = (ushort*)take((size_t)NLAYER * DD * DI * 2);
  float*  convWt = (float*) take((size_t)NLAYER * 4 * DI * 4);

  {
    int total = NLAYER * E2 * DD / 4 + NLAYER * DD * DI / 4;
    k_cvtA<<<(total + 255) / 256, 256, 0, stream>>>(in_W, out_W, wInBf, wOutBf);
  }
  {
    int total = NLAYER * 80 * DI / 4 + NLAYER * DI * 64 + NLAYER * DI * 4;
    k_cvtB<<<(total + 255) / 256, 256, 0, stream>>>(xp_W, dt_W, conv_W,
                                                    wXpBf, wDtBf, convWt);
  }
  k_embed<<<(MROWS * (DD / 4) + 255) / 256, 256, 0, stream>>>(ids, wte, wpe, resid);

  for (int i = 0; i < NLAYER; ++i) {
    k_ln<<<MROWS, 256, 0, stream>>>(hidP, resid,
                                    ln_g + (size_t)i * DD, ln_b + (size_t)i * DD,
                                    h_bf, i > 0 ? 1 : 0);

    { dim3 g(E2 / 128, MROWS / 64, 1);    // 24 x 32 = 768 blocks
      k_gemm64<1><<<g, 256, 0, stream>>>(h_bf, wInBf + (size_t)i * E2 * DD,
                                         (void*)xz, nullptr, E2, DD, DD / 64); }

    { dim3 g(1, MROWS / 64, XPZ);         // 32 x 12 = 384 blocks, 2 K-steps
      k_xpconv<<<g, 256, 0, stream>>>(xz, wXpBf + (size_t)i * 80 * DI,
                                      convWt + (size_t)i * 4 * DI,
                                      conv_b + (size_t)i * DI, xibf, xpPart); }

    k_comb_xp<<<(MROWS * 80 + 255) / 256, 256, 0, stream>>>(xpPart, dblb, dtbf);

    { dim3 g(DI / 128, MROWS / 64, 1);    // 12 x 32 = 384 blocks, K=64
      k_gemm64<2><<<g, 256, 0, stream>>>(dtbf, wDtBf + (size_t)i * DI * 64,
                                         (void*)delta, dt_b + (size_t)i * DI, DI, 64, 1); }

    { dim3 g(DI / 16, BB);                // 96 x 4 = 384 blocks
      k_scan_f<<<g, 256, 0, stream>>>(delta, xibf, dblb, xz, A_log, Dres, ybf, i); }

    { dim3 g(DD / 128, MROWS / 64, OZ);   // 6 x 32 x 2 = 384 blocks, 12 stages
      k_gemm64<3><<<g, 256, 0, stream>>>(ybf, wOutBf + (size_t)i * DD * DI,
                                         (void*)hidP, nullptr, DD, DI, DI / 64 / OZ); }
  }

  k_final<<<MROWS, 256, 0, stream>>>(resid, hidP, nf_g, nf_b,
                                     fin_g, fin_b, (float*)d_out);
}